// Round 14
// baseline (634.342 us; speedup 1.0000x reference)
//
#include <hip/hip_runtime.h>
#include <stdint.h>

// ---------- common ----------
typedef __attribute__((ext_vector_type(8))) short bf16x8;
typedef __attribute__((ext_vector_type(4))) float f32x4;
typedef __attribute__((ext_vector_type(16))) float f32x16;

#define S_LEN 2048
#define D_MODEL 2048
#define NQH 16
#define NKVH 4
#define HDIM 128
#define BATCH 4

__device__ __forceinline__ float bf2f(unsigned short s) {
  union { unsigned u; float f; } v; v.u = ((unsigned)s) << 16; return v.f;
}
__device__ __forceinline__ unsigned short f2bf(float f) {
  union { float f; unsigned u; } v; v.f = f;
  unsigned r = v.u + 0x7FFFu + ((v.u >> 16) & 1u);
  return (unsigned short)(r >> 16);
}
__device__ __forceinline__ f32x4 fzero() {
  f32x4 v; v[0]=0.f; v[1]=0.f; v[2]=0.f; v[3]=0.f; return v;
}
__device__ __forceinline__ void async16(const void* g, void* l) {
  __builtin_amdgcn_global_load_lds(
      (const __attribute__((address_space(1))) unsigned int*)g,
      (__attribute__((address_space(3))) unsigned int*)l, 16, 0, 0);
}
__device__ __forceinline__ unsigned cvtpk(float lo, float hi) {
  unsigned r;
  asm("v_cvt_pk_bf16_f32 %0, %1, %2" : "=v"(r) : "v"(lo), "v"(hi));
  return r;
}

// ---------- fp32 -> bf16 bulk convert (x) ----------
__global__ void k_convert_x(const float* __restrict__ x, unsigned short* __restrict__ xb, int n4) {
  int stride = gridDim.x * blockDim.x;
  for (int i = blockIdx.x * blockDim.x + threadIdx.x; i < n4; i += stride) {
    float4 v = ((const float4*)x)[i];
    ushort4 o;
    o.x = f2bf(v.x); o.y = f2bf(v.y); o.z = f2bf(v.z); o.w = f2bf(v.w);
    ((ushort4*)xb)[i] = o;
  }
}

// ---------- all 4 weight transposes in one launch ----------
__global__ void k_transpose_all(const float* __restrict__ Wq, const float* __restrict__ Wk,
                                const float* __restrict__ Wv, const float* __restrict__ Wo,
                                unsigned short* __restrict__ Wt, unsigned short* __restrict__ Wot) {
  __shared__ float tile[32][33];
  int bid = blockIdx.x;
  const float* W; unsigned short* D; int N, nx;
  if (bid < 4096)      { W = Wq; D = Wt;                          N = 2048; nx = 64; }
  else if (bid < 5120) { W = Wk; D = Wt + (size_t)2048 * 2048;    N = 512;  nx = 16; bid -= 4096; }
  else if (bid < 6144) { W = Wv; D = Wt + (size_t)2560 * 2048;    N = 512;  nx = 16; bid -= 5120; }
  else                 { W = Wo; D = Wot;                         N = 2048; nx = 64; bid -= 6144; }
  int tx = threadIdx.x & 31, ty = threadIdx.x >> 5;
  int n0 = (bid % nx) * 32, k0 = (bid / nx) * 32;
  #pragma unroll
  for (int i = 0; i < 4; ++i)
    tile[ty + i*8][tx] = W[(size_t)(k0 + ty + i*8) * N + n0 + tx];
  __syncthreads();
  #pragma unroll
  for (int i = 0; i < 4; ++i)
    D[(size_t)(n0 + ty + i*8) * 2048 + k0 + tx] = f2bf(tile[tx][ty + i*8]);
}

// ---------- RoPE on K only (Q is roped inside flash) ----------
__global__ void k_ropeK(unsigned short* __restrict__ Kb, const float* __restrict__ fc,
                        const int* __restrict__ start_pos, int total) {
  int sp = start_pos[0];
  int stride = gridDim.x * blockDim.x;
  for (int i = blockIdx.x * blockDim.x + threadIdx.x; i < total; i += stride) {
    int d2 = i & 63;
    int s = (i >> 6) & (S_LEN - 1);
    unsigned v = ((unsigned*)Kb)[i];
    float x0 = bf2f((unsigned short)(v & 0xFFFFu));
    float x1 = bf2f((unsigned short)(v >> 16));
    float c  = fc[((size_t)(sp + s) * 64 + d2) * 2];
    float sn = fc[((size_t)(sp + s) * 64 + d2) * 2 + 1];
    float y0 = x0 * c - x1 * sn;
    float y1 = x0 * sn + x1 * c;
    ((unsigned*)Kb)[i] = (unsigned)f2bf(y0) | ((unsigned)f2bf(y1) << 16);
  }
}

#define BARRIER() __builtin_amdgcn_s_barrier()
#define LGKM0()  do { asm volatile("s_waitcnt lgkmcnt(0)" ::: "memory"); \
                      __builtin_amdgcn_sched_barrier(0); } while (0)
#define VMCNT6() asm volatile("s_waitcnt vmcnt(6)" ::: "memory")
#define VMCNT4() asm volatile("s_waitcnt vmcnt(4)" ::: "memory")
#define VMCNT0() asm volatile("s_waitcnt vmcnt(0)" ::: "memory")

__device__ __forceinline__ bf16x8 ldsrd(const unsigned short* L, int row, int kk, int g) {
  int Xs = (kk * 64 + g * 16) ^ ((row & 7) << 4);
  return *(const bf16x8*)&L[row * 64 + (Xs >> 1)];
}
// wave-cooperative: write 8 rows at rowbase (multiple of 8) of [256][64] tile
__device__ __forceinline__ void stage8(const unsigned short* __restrict__ G, int gbase,
                                       int k0, unsigned short* lds, int rowbase, int lane) {
  int row = rowbase + (lane >> 3);
  int col8 = (lane & 7) ^ ((lane >> 3) & 7);
  async16(G + (size_t)(gbase + row) * 2048 + k0 + col8 * 8, lds + rowbase * 64 + lane * 8);
}

const float SCL2E_H = 0.08838834764831845f * 1.4426950408889634f;  // scale * log2(e)

// ============ Q GEMM: 256x256 4-phase, grid 32x8=256 ============
__global__ __launch_bounds__(512, 2) void k_gemm_q(
    const unsigned short* __restrict__ A, const unsigned short* __restrict__ Bt,
    const float* __restrict__ bq, unsigned short* __restrict__ Qo)
{
  __shared__ __align__(16) unsigned short Abuf[2][256 * 64];
  __shared__ __align__(16) unsigned short Bbuf[2][256 * 64];
  const int NT = 32, NXT = 8;
  const int tid = threadIdx.x, lane = tid & 63, w = tid >> 6;
  const int lr = lane & 15, g = lane >> 4;
  const int wm = w >> 2, wn = w & 3;

  int nwg = NXT * 32;
  int cpx = nwg >> 3;
  int bid = blockIdx.x;
  int swz = (bid & 7) * cpx + (bid >> 3);
  const int by = swz / NXT, bx = swz % NXT;
  const int mbase = by * 256, nbase = bx * 256;

  #define ST_AQ02(tt) if ((tt) < NT) { unsigned short* L = Abuf[(tt) & 1]; int k0 = (tt) * 64; \
    _Pragma("unroll") for (int it = 0; it < 2; ++it) { int sub = it * 8 + w; \
      stage8(A, mbase, k0, L, (sub >> 3) * 128 + (sub & 7) * 8, lane); } }
  #define ST_AQ13(tt) if ((tt) < NT) { unsigned short* L = Abuf[(tt) & 1]; int k0 = (tt) * 64; \
    _Pragma("unroll") for (int it = 0; it < 2; ++it) { int sub = it * 8 + w; \
      stage8(A, mbase, k0, L, 64 + (sub >> 3) * 128 + (sub & 7) * 8, lane); } }
  #define ST_BS0(tt) if ((tt) < NT) { unsigned short* L = Bbuf[(tt) & 1]; int k0 = (tt) * 64; \
    _Pragma("unroll") for (int it = 0; it < 2; ++it) { int sub = it * 8 + w; \
      stage8(Bt, nbase, k0, L, (sub >> 2) * 64 + (sub & 3) * 8, lane); } }
  #define ST_BS1(tt) if ((tt) < NT) { unsigned short* L = Bbuf[(tt) & 1]; int k0 = (tt) * 64; \
    _Pragma("unroll") for (int it = 0; it < 2; ++it) { int sub = it * 8 + w; \
      stage8(Bt, nbase, k0, L, 32 + (sub >> 2) * 64 + (sub & 3) * 8, lane); } }

  f32x4 acc[8][4];
  #pragma unroll
  for (int m = 0; m < 8; ++m)
    #pragma unroll
    for (int n = 0; n < 4; ++n) acc[m][n] = fzero();

  ST_AQ02(0); ST_AQ13(0); ST_BS0(0); ST_BS1(0);
  ST_AQ02(1); ST_BS1(1);
  VMCNT4();
  BARRIER();

  bf16x8 a[2][4], b[2][2];

  for (int t = 0; t < NT; ++t) {
    const unsigned short* Al = Abuf[t & 1];
    const unsigned short* Bl = Bbuf[t & 1];

    #pragma unroll
    for (int kk = 0; kk < 2; ++kk) {
      #pragma unroll
      for (int m = 0; m < 4; ++m) a[kk][m] = ldsrd(Al, wm * 128 + m * 16 + lr, kk, g);
      #pragma unroll
      for (int n = 0; n < 2; ++n) b[kk][n] = ldsrd(Bl, wn * 64 + n * 16 + lr, kk, g);
    }
    ST_AQ13(t + 1);
    BARRIER(); LGKM0();
    __builtin_amdgcn_s_setprio(1);
    #pragma unroll
    for (int kk = 0; kk < 2; ++kk)
      #pragma unroll
      for (int m = 0; m < 4; ++m)
        #pragma unroll
        for (int n = 0; n < 2; ++n)
          acc[m][n] = __builtin_amdgcn_mfma_f32_16x16x32_bf16(a[kk][m], b[kk][n], acc[m][n], 0, 0, 0);
    __builtin_amdgcn_s_setprio(0);
    BARRIER();

    #pragma unroll
    for (int kk = 0; kk < 2; ++kk)
      #pragma unroll
      for (int n = 0; n < 2; ++n) b[kk][n] = ldsrd(Bl, wn * 64 + (2 + n) * 16 + lr, kk, g);
    ST_BS0(t + 1);
    BARRIER(); LGKM0();
    __builtin_amdgcn_s_setprio(1);
    #pragma unroll
    for (int kk = 0; kk < 2; ++kk)
      #pragma unroll
      for (int m = 0; m < 4; ++m)
        #pragma unroll
        for (int n = 0; n < 2; ++n)
          acc[m][2 + n] = __builtin_amdgcn_mfma_f32_16x16x32_bf16(a[kk][m], b[kk][n], acc[m][2 + n], 0, 0, 0);
    __builtin_amdgcn_s_setprio(0);
    BARRIER();

    #pragma unroll
    for (int kk = 0; kk < 2; ++kk)
      #pragma unroll
      for (int m = 0; m < 4; ++m) a[kk][m] = ldsrd(Al, wm * 128 + 64 + m * 16 + lr, kk, g);
    ST_AQ02(t + 2);
    BARRIER(); LGKM0();
    __builtin_amdgcn_s_setprio(1);
    #pragma unroll
    for (int kk = 0; kk < 2; ++kk)
      #pragma unroll
      for (int m = 0; m < 4; ++m)
        #pragma unroll
        for (int n = 0; n < 2; ++n)
          acc[4 + m][2 + n] = __builtin_amdgcn_mfma_f32_16x16x32_bf16(a[kk][m], b[kk][n], acc[4 + m][2 + n], 0, 0, 0);
    __builtin_amdgcn_s_setprio(0);
    BARRIER();

    #pragma unroll
    for (int kk = 0; kk < 2; ++kk)
      #pragma unroll
      for (int n = 0; n < 2; ++n) b[kk][n] = ldsrd(Bl, wn * 64 + n * 16 + lr, kk, g);
    ST_BS1(t + 2);
    VMCNT4();
    BARRIER(); LGKM0();
    __builtin_amdgcn_s_setprio(1);
    #pragma unroll
    for (int kk = 0; kk < 2; ++kk)
      #pragma unroll
      for (int m = 0; m < 4; ++m)
        #pragma unroll
        for (int n = 0; n < 2; ++n)
          acc[4 + m][n] = __builtin_amdgcn_mfma_f32_16x16x32_bf16(a[kk][m], b[kk][n], acc[4 + m][n], 0, 0, 0);
    __builtin_amdgcn_s_setprio(0);
    BARRIER();
  }

  #pragma unroll
  for (int n = 0; n < 4; ++n) {
    const int ng = nbase + wn * 64 + n * 16 + lr;
    const int hh = ng >> 7, dd = ng & 127;
    const float bias = bq[ng];
    #pragma unroll
    for (int m = 0; m < 8; ++m)
      #pragma unroll
      for (int i = 0; i < 4; ++i) {
        int mg = mbase + wm * 128 + m * 16 + g * 4 + i;
        int bb = mg >> 11, s = mg & 2047;
        float val = (acc[m][n][i] + bias) * SCL2E_H;
        Qo[((size_t)(bb * NQH + hh) * S_LEN + s) * HDIM + dd] = f2bf(val);
      }
  }
  #undef ST_AQ02
  #undef ST_AQ13
  #undef ST_BS0
  #undef ST_BS1
}

// ============ KV GEMM: 256x128 2-phase triple-buffered, N=1024, grid 32x8=256 ============
__global__ __launch_bounds__(512, 2) void k_gemm_kv(
    const unsigned short* __restrict__ A, const unsigned short* __restrict__ Bt,
    const float* __restrict__ bk, const float* __restrict__ bv,
    unsigned short* __restrict__ Ko, unsigned short* __restrict__ Vto)
{
  __shared__ __align__(16) unsigned short Ab[3][256 * 64];
  __shared__ __align__(16) unsigned short Bb[3][128 * 64];
  const int NT = 32, NXT = 8;
  const int tid = threadIdx.x, lane = tid & 63, w = tid >> 6;
  const int lr = lane & 15, g = lane >> 4;
  const int wm = w >> 1, wn = w & 1;

  int nwg = NXT * 32;
  int cpx = nwg >> 3;
  int bid = blockIdx.x;
  int swz = (bid & 7) * cpx + (bid >> 3);
  const int by = swz / NXT, bx = swz % NXT;
  const int mbase = by * 256, nbase = bx * 128;

  #define ST_A(tt) { unsigned short* L = Ab[(tt) % 3]; int k0 = (tt) * 64; \
    _Pragma("unroll") for (int it = 0; it < 4; ++it) { int c = tid + it * 512; \
      int row = c >> 3, col8 = (c & 7) ^ (row & 7); \
      async16(A + (size_t)(mbase + row) * 2048 + k0 + col8 * 8, L + c * 8); } }
  #define ST_B(tt) { unsigned short* L = Bb[(tt) % 3]; int k0 = (tt) * 64; \
    _Pragma("unroll") for (int it = 0; it < 2; ++it) { int c = tid + it * 512; \
      int row = c >> 3, col8 = (c & 7) ^ (row & 7); \
      async16(Bt + (size_t)(nbase + row) * 2048 + k0 + col8 * 8, L + c * 8); } }

  f32x4 acc[4][4];
  #pragma unroll
  for (int m = 0; m < 4; ++m)
    #pragma unroll
    for (int n = 0; n < 4; ++n) acc[m][n] = fzero();

  ST_A(0); ST_B(0); ST_A(1); ST_B(1);
  VMCNT6();
  BARRIER();

  for (int t = 0; t < NT; ++t) {
    const unsigned short* Al = Ab[t % 3];
    const unsigned short* Bl = Bb[t % 3];
    bf16x8 a[2][4], b[2][2];

    #pragma unroll
    for (int kk = 0; kk < 2; ++kk) {
      #pragma unroll
      for (int m = 0; m < 4; ++m) a[kk][m] = ldsrd(Al, wm * 64 + m * 16 + lr, kk, g);
      #pragma unroll
      for (int n = 0; n < 2; ++n) b[kk][n] = ldsrd(Bl, wn * 64 + n * 16 + lr, kk, g);
    }
    if (t + 2 < NT) ST_A(t + 2);
    BARRIER(); LGKM0();
    __builtin_amdgcn_s_setprio(1);
    #pragma unroll
    for (int kk = 0; kk < 2; ++kk)
      #pragma unroll
      for (int m = 0; m < 4; ++m)
        #pragma unroll
        for (int n = 0; n < 2; ++n)
          acc[m][n] = __builtin_amdgcn_mfma_f32_16x16x32_bf16(a[kk][m], b[kk][n], acc[m][n], 0, 0, 0);
    __builtin_amdgcn_s_setprio(0);
    BARRIER();

    #pragma unroll
    for (int kk = 0; kk < 2; ++kk)
      #pragma unroll
      for (int n = 0; n < 2; ++n) b[kk][n] = ldsrd(Bl, wn * 64 + (2 + n) * 16 + lr, kk, g);
    if (t + 2 < NT) { ST_B(t + 2); VMCNT6(); } else { VMCNT0(); }
    BARRIER(); LGKM0();
    __builtin_amdgcn_s_setprio(1);
    #pragma unroll
    for (int kk = 0; kk < 2; ++kk)
      #pragma unroll
      for (int m = 0; m < 4; ++m)
        #pragma unroll
        for (int n = 0; n < 2; ++n)
          acc[m][2 + n] = __builtin_amdgcn_mfma_f32_16x16x32_bf16(a[kk][m], b[kk][n], acc[m][2 + n], 0, 0, 0);
    __builtin_amdgcn_s_setprio(0);
    BARRIER();
  }

  #pragma unroll
  for (int n = 0; n < 4; ++n) {
    const int ng = nbase + wn * 64 + n * 16 + lr;        // 0..1023
    const bool isK = (ng < 512);
    const int nn = isK ? ng : ng - 512;
    const int hh = nn >> 7, dd = nn & 127;
    const float bias = isK ? bk[nn] : bv[nn];
    #pragma unroll
    for (int m = 0; m < 4; ++m)
      #pragma unroll
      for (int i = 0; i < 4; ++i) {
        int mg = mbase + wm * 64 + m * 16 + g * 4 + i;
        int bb = mg >> 11, s = mg & 2047;
        float val = acc[m][n][i] + bias;
        if (isK) {
          Ko[((size_t)(bb * NKVH + hh) * S_LEN + s) * HDIM + dd] = f2bf(val);
        } else {
          Vto[((size_t)(bb * NKVH + hh) * HDIM + dd) * S_LEN + s] = f2bf(val);
        }
      }
  }
  #undef ST_A
  #undef ST_B
}

// ============ OUT GEMM: 256x256 4-phase, grid 256 ============
__global__ __launch_bounds__(512, 2) void k_gemm_out256(
    const unsigned short* __restrict__ A, const unsigned short* __restrict__ Bt,
    float* __restrict__ Cf)
{
  __shared__ __align__(16) unsigned short Abuf[2][256 * 64];
  __shared__ __align__(16) unsigned short Bbuf[2][256 * 64];
  const int NT = 32, NXT = 8;
  const int tid = threadIdx.x, lane = tid & 63, w = tid >> 6;
  const int lr = lane & 15, g = lane >> 4;
  const int wm = w >> 2, wn = w & 3;

  int nwg = NXT * 32;
  int cpx = nwg >> 3;
  int bid = blockIdx.x;
  int swz = (bid & 7) * cpx + (bid >> 3);
  const int by = swz / NXT, bx = swz % NXT;
  const int mbase = by * 256, nbase = bx * 256;

  #define ST_AQ02(tt) if ((tt) < NT) { unsigned short* L = Abuf[(tt) & 1]; int k0 = (tt) * 64; \
    _Pragma("unroll") for (int it = 0; it < 2; ++it) { int sub = it * 8 + w; \
      stage8(A, mbase, k0, L, (sub >> 3) * 128 + (sub & 7) * 8, lane); } }
  #define ST_AQ13(tt) if ((tt) < NT) { unsigned short* L = Abuf[(tt) & 1]; int k0 = (tt) * 64; \
    _Pragma("unroll") for (int it = 0; it < 2; ++it) { int sub = it * 8 + w; \
      stage8(A, mbase, k0, L, 64 + (sub >> 3) * 128 + (sub & 7) * 8, lane); } }
  #define ST_BS0(tt) if ((tt) < NT) { unsigned short* L = Bbuf[(tt) & 1]; int k0 = (tt) * 64; \
    _Pragma("unroll") for (int it = 0; it < 2; ++it) { int sub = it * 8 + w; \
      stage8(Bt, nbase, k0, L, (sub >> 2) * 64 + (sub & 3) * 8, lane); } }
  #define ST_BS1(tt) if ((tt) < NT) { unsigned short* L = Bbuf[(tt) & 1]; int k0 = (tt) * 64; \
    _Pragma("unroll") for (int it = 0; it < 2; ++it) { int sub = it * 8 + w; \
      stage8(Bt, nbase, k0, L, 32 + (sub >> 2) * 64 + (sub & 3) * 8, lane); } }

  f32x4 acc[8][4];
  #pragma unroll
  for (int m = 0; m < 8; ++m)
    #pragma unroll
    for (int n = 0; n < 4; ++n) acc[m][n] = fzero();

  ST_AQ02(0); ST_AQ13(0); ST_BS0(0); ST_BS1(0);
  ST_AQ02(1); ST_BS1(1);
  VMCNT4();
  BARRIER();

  bf16x8 a[2][4], b[2][2];

  for (int t = 0; t < NT; ++t) {
    const unsigned short* Al = Abuf[t & 1];
    const unsigned short* Bl = Bbuf[t & 1];

    #pragma unroll
    for (int kk = 0; kk < 2; ++kk) {
      #pragma unroll
      for (int m = 0; m < 4; ++m) a[kk][m] = ldsrd(Al, wm * 128 + m * 16 + lr, kk, g);
      #pragma unroll
      for (int n = 0; n < 2; ++n) b[kk][n] = ldsrd(Bl, wn * 64 + n * 16 + lr, kk, g);
    }
    ST_AQ13(t + 1);
    BARRIER(); LGKM0();
    __builtin_amdgcn_s_setprio(1);
    #pragma unroll
    for (int kk = 0; kk < 2; ++kk)
      #pragma unroll
      for (int m = 0; m < 4; ++m)
        #pragma unroll
        for (int n = 0; n < 2; ++n)
          acc[m][n] = __builtin_amdgcn_mfma_f32_16x16x32_bf16(a[kk][m], b[kk][n], acc[m][n], 0, 0, 0);
    __builtin_amdgcn_s_setprio(0);
    BARRIER();

    #pragma unroll
    for (int kk = 0; kk < 2; ++kk)
      #pragma unroll
      for (int n = 0; n < 2; ++n) b[kk][n] = ldsrd(Bl, wn * 64 + (2 + n) * 16 + lr, kk, g);
    ST_BS0(t + 1);
    BARRIER(); LGKM0();
    __builtin_amdgcn_s_setprio(1);
    #pragma unroll
    for (int kk = 0; kk < 2; ++kk)
      #pragma unroll
      for (int m = 0; m < 4; ++m)
        #pragma unroll
        for (int n = 0; n < 2; ++n)
          acc[m][2 + n] = __builtin_amdgcn_mfma_f32_16x16x32_bf16(a[kk][m], b[kk][n], acc[m][2 + n], 0, 0, 0);
    __builtin_amdgcn_s_setprio(0);
    BARRIER();

    #pragma unroll
    for (int kk = 0; kk < 2; ++kk)
      #pragma unroll
      for (int m = 0; m < 4; ++m) a[kk][m] = ldsrd(Al, wm * 128 + 64 + m * 16 + lr, kk, g);
    ST_AQ02(t + 2);
    BARRIER(); LGKM0();
    __builtin_amdgcn_s_setprio(1);
    #pragma unroll
    for (int kk = 0; kk < 2; ++kk)
      #pragma unroll
      for (int m = 0; m < 4; ++m)
        #pragma unroll
        for (int n = 0; n < 2; ++n)
          acc[4 + m][2 + n] = __builtin_amdgcn_mfma_f32_16x16x32_bf16(a[kk][m], b[kk][n], acc[4 + m][2 + n], 0, 0, 0);
    __builtin_amdgcn_s_setprio(0);
    BARRIER();

    #pragma unroll
    for (int kk = 0; kk < 2; ++kk)
      #pragma unroll
      for (int n = 0; n < 2; ++n) b[kk][n] = ldsrd(Bl, wn * 64 + n * 16 + lr, kk, g);
    ST_BS1(t + 2);
    VMCNT4();
    BARRIER(); LGKM0();
    __builtin_amdgcn_s_setprio(1);
    #pragma unroll
    for (int kk = 0; kk < 2; ++kk)
      #pragma unroll
      for (int m = 0; m < 4; ++m)
        #pragma unroll
        for (int n = 0; n < 2; ++n)
          acc[4 + m][n] = __builtin_amdgcn_mfma_f32_16x16x32_bf16(a[kk][m], b[kk][n], acc[4 + m][n], 0, 0, 0);
    __builtin_amdgcn_s_setprio(0);
    BARRIER();
  }

  #pragma unroll
  for (int m = 0; m < 8; ++m)
    #pragma unroll
    for (int n = 0; n < 4; ++n)
      #pragma unroll
      for (int i = 0; i < 4; ++i) {
        int mg = mbase + wm * 128 + m * 16 + g * 4 + i;
        int ng = nbase + wn * 64 + n * 16 + lr;
        Cf[(size_t)mg * 2048 + ng] = acc[m][n][i];
      }
  #undef ST_AQ02
  #undef ST_AQ13
  #undef ST_BS0
  #undef ST_BS1
}

// ---------- flash v9: 8 waves x 32 q-rows (QBLK=256), 64KB LDS, 2 blocks/CU (16 waves/CU),
// fused Q-rope, exp2 domain, defer-max, diag-only mask ----------
// grid 256 = 64 bh x 4 tile-pairs {tp, 7-tp}; 36 KV-iters per block.
__global__ __launch_bounds__(512, 4) void k_flash2(
    const unsigned short* __restrict__ Q, const unsigned short* __restrict__ K,
    const unsigned short* __restrict__ Vt, unsigned short* __restrict__ O,
    const float* __restrict__ fc, const int* __restrict__ start_pos)
{
  __shared__ __align__(16) unsigned short SH[32768];  // 64KB: 2 x (K 16KB + V 16KB); epilogue reuses

  const int tid = threadIdx.x;
  const int lane = tid & 63;
  const int w = tid >> 6;        // 0..7
  const int ql = lane & 31;
  const int hi = lane >> 5;

  const int bh = blockIdx.x >> 2;
  const int tp = blockIdx.x & 3;
  const int b = bh >> 4, h = bh & 15;
  const int kh = h >> 2;
  const int sp = start_pos[0];

  const unsigned short* Qbase = Q + (size_t)(b * NQH + h) * S_LEN * HDIM;
  const unsigned short* Kbase = K + (size_t)(b * NKVH + kh) * S_LEN * HDIM;
  const unsigned short* Vtb   = Vt + (size_t)(b * NKVH + kh) * HDIM * S_LEN;

  // stage KV tile jj into buffer jj&1 (4 loads/thread: 2 K + 2 V)
  #define STAGEKV(jj) { unsigned short* Kd = SH + ((jj) & 1) * 16384; \
    unsigned short* Vd = Kd + 8192; \
    _Pragma("unroll") for (int it = 0; it < 2; ++it) { \
      int c = tid + it * 512; int row = c >> 4, col = c & 15; \
      int lcol = (col & 8) | ((col ^ (row & 7)) & 7); \
      async16(Kbase + (size_t)((jj) * 64 + row) * HDIM + lcol * 8, Kd + c * 8); } \
    _Pragma("unroll") for (int it = 0; it < 2; ++it) { \
      int c = tid + it * 512; int row = c >> 3, col = c & 7; \
      int lcol = col ^ (row & 7); \
      async16(Vtb + (size_t)row * S_LEN + (jj) * 64 + lcol * 8, Vd + c * 8); } }

  #pragma unroll 1
  for (int half = 0; half < 2; ++half) {
    const int t = half ? (7 - tp) : tp;
    const int nkv = 4 * t + 4;
    const int qg = t * 256 + w * 32 + ql;
    const int jd = 4 * t + (w >> 1);   // wave's diagonal iteration
    const int ql2 = (w & 1) * 32 + ql; // q row within the diagonal 64-block

    __syncthreads();  // protect LDS reuse across halves

    // Q load + in-register RoPE (pairs (2u,2u+1) are lane-local in the fragment)
    bf16x8 qf[8];
    {
      const unsigned short* qp = Qbase + (size_t)qg * HDIM;
      const float* fcrow = fc + (size_t)(sp + qg) * 128;
      #pragma unroll
      for (int dd = 0; dd < 8; ++dd) {
        bf16x8 raw = *(const bf16x8*)(qp + dd * 16 + hi * 8);
        int d2b = (dd * 16 + hi * 8) >> 1;
        union { unsigned u[4]; bf16x8 v; } out;
        #pragma unroll
        for (int u2 = 0; u2 < 4; ++u2) {
          float x0 = bf2f((unsigned short)raw[2 * u2]);
          float x1 = bf2f((unsigned short)raw[2 * u2 + 1]);
          float2 cs = *(const float2*)&fcrow[(d2b + u2) * 2];
          out.u[u2] = cvtpk(x0 * cs.x - x1 * cs.y, x0 * cs.y + x1 * cs.x);
        }
        qf[dd] = out.v;
      }
    }

    float m_r = -1e30f, l_r = 0.f;
    f32x16 oA[4];
    #pragma unroll
    for (int db = 0; db < 4; ++db)
      #pragma unroll
      for (int r = 0; r < 16; ++r) oA[db][r] = 0.f;

    STAGEKV(0);
    __syncthreads();

    for (int j = 0; j < nkv; ++j) {
      const unsigned short* Kl = SH + (j & 1) * 16384;
      const unsigned short* Vl = Kl + 8192;

      if (j + 1 < nkv) STAGEKV(j + 1);

      if (j <= jd) {
        f32x16 p0, p1;
        #pragma unroll
        for (int r = 0; r < 16; ++r) { p0[r] = 0.f; p1[r] = 0.f; }
        __builtin_amdgcn_s_setprio(1);
        #pragma unroll
        for (int dd = 0; dd < 8; ++dd) {
          const int off = (((dd * 32 + hi * 16) ^ ((ql & 7) << 4)) >> 1);
          bf16x8 a0 = *(const bf16x8*)&Kl[ql * 128 + off];
          bf16x8 a1 = *(const bf16x8*)&Kl[(32 + ql) * 128 + off];
          p0 = __builtin_amdgcn_mfma_f32_32x32x16_bf16(a0, qf[dd], p0, 0, 0, 0);
          p1 = __builtin_amdgcn_mfma_f32_32x32x16_bf16(a1, qf[dd], p1, 0, 0, 0);
        }
        __builtin_amdgcn_s_setprio(0);

        // causal mask: diagonal iteration only (j<jd needs none; j>jd skipped)
        if (j == jd) {
          #pragma unroll
          for (int r = 0; r < 16; ++r) {
            const int klh = (r & 3) + 8 * (r >> 2) + 4 * hi;
            if (klh > ql2) p0[r] = -1e30f;
            if (klh + 32 > ql2) p1[r] = -1e30f;
          }
        }

        // online softmax with defer-max (THR=8 in log2 domain)
        float pm = -1e30f;
        #pragma unroll
        for (int r = 0; r < 16; ++r) pm = fmaxf(pm, fmaxf(p0[r], p1[r]));
        pm = fmaxf(pm, __shfl_xor(pm, 32));
        if (!__all(pm - m_r <= 8.0f)) {
          const float mn = fmaxf(m_r, pm);
          const float corr = exp2f(m_r - mn);
          m_r = mn;
          l_r *= corr;
          #pragma unroll
          for (int db = 0; db < 4; ++db)
            #pragma unroll
            for (int r = 0; r < 16; ++r) oA[db][r] *= corr;
        }
        float rs = 0.f;
        #pragma unroll
        for (int r = 0; r < 16; ++r) {
          p0[r] = exp2f(p0[r] - m_r);
          p1[r] = exp2f(p1[r] - m_r);
          rs += p0[r] + p1[r];
        }
        rs += __shfl_xor(rs, 32);
        l_r += rs;

        bf16x8 pb[4];
        {
          unsigned Wv[8], W2v[8];
          #pragma unroll
          for (int d = 0; d < 4; ++d) {
            Wv[d]      = cvtpk(p0[4*d],     p0[4*d + 1]);
            W2v[d]     = cvtpk(p0[4*d + 2], p0[4*d + 3]);
            Wv[4 + d]  = cvtpk(p1[4*d],     p1[4*d + 1]);
            W2v[4 + d] = cvtpk(p1[4*d + 2], p1[4*d + 3]);
          }
          #pragma unroll
          for (int kt = 0; kt < 2; ++kt) {
            #pragma unroll
            for (int s = 0; s < 2; ++s) {
              unsigned ownW   = hi ? Wv[kt*4 + 2*s + 1]  : Wv[kt*4 + 2*s];
              unsigned sendW  = hi ? Wv[kt*4 + 2*s]      : Wv[kt*4 + 2*s + 1];
              unsigned recvW  = (unsigned)__shfl_xor((int)sendW, 32);
              unsigned ownW2  = hi ? W2v[kt*4 + 2*s + 1] : W2v[kt*4 + 2*s];
              unsigned sendW2 = hi ? W2v[kt*4 + 2*s]     : W2v[kt*4 + 2*s + 1];
              unsigned recvW2 = (unsigned)__shfl_xor((int)sendW2, 32);
              union { unsigned u[4]; bf16x8 v; } pk;
              pk.u[0] = hi ? recvW  : ownW;
              pk.u[1] = hi ? recvW2 : ownW2;
              pk.u[2] = hi ? ownW   : recvW;
              pk.u[3] = hi ? ownW2  : recvW2;
              pb[kt*2 + s] = pk.v;
            }
          }
        }

        __builtin_amdgcn_s_setprio(1);
        #pragma unroll
        for (int ks = 0; ks < 4; ++ks) {
          #pragma unroll
          for (int db = 0; db < 4; ++db) {
            const int off = (((ks * 32 + hi * 16) ^ ((ql & 7) << 4)) >> 1);
            bf16x8 av = *(const bf16x8*)&Vl[(db * 32 + ql) * 64 + off];
            oA[db] = __builtin_amdgcn_mfma_f32_32x32x16_bf16(av, pb[ks], oA[db], 0, 0, 0);
          }
        }
        __builtin_amdgcn_s_setprio(0);
      }
      __syncthreads();
    }

    // epilogue: O^T -> LDS (transpose, swizzled) -> coalesced global (256 rows x 256B = 64KB)
    {
      const float invl = 1.f / l_r;
      const int qloc = w * 32 + ql;
      #pragma unroll
      for (int db = 0; db < 4; ++db)
        #pragma unroll
        for (int g4 = 0; g4 < 4; ++g4) {
          unsigned lo  = cvtpk(oA[db][g4*4 + 0] * invl, oA[db][g4*4 + 1] * invl);
          unsigned hi2 = cvtpk(oA[db][g4*4 + 2] * invl, oA[db][g4*4 + 3] * invl);
          int byteoff = qloc * 256 + ((db * 64 + g4 * 16 + hi * 8) ^ ((qloc & 7) << 4));
          *(uint2*)((char*)SH + byteoff) = make_uint2(lo, hi2);
        }
    }
    __syncthreads();
    {
      const int q2 = tid >> 1, hf = tid & 1;
      unsigned short* orow = O + ((size_t)(b * S_LEN + t * 256 + q2)) * D_MODEL + h * HDIM + hf * 64;
      #pragma unroll
      for (int u = 0; u < 8; ++u) {
        int byteoff = q2 * 256 + ((hf * 128 + u * 16) ^ ((q2 & 7) << 4));
        bf16x8 v = *(const bf16x8*)((const char*)SH + byteoff);
        *(bf16x8*)(orow + u * 8) = v;
      }
    }
  }
  #undef STAGEKV
}

// ---------- launch ----------
extern "C" void kernel_launch(void* const* d_in, const int* in_sizes, int n_in,
                              void* d_out, int out_size, void* d_ws, size_t ws_size,
                              hipStream_t stream) {
  (void)in_sizes; (void)n_in; (void)out_size; (void)ws_size;
  const float* x  = (const float*)d_in[0];
  const float* fc = (const float*)d_in[1];
  const float* Wq = (const float*)d_in[2];
  const float* bq = (const float*)d_in[3];
  const float* Wk = (const float*)d_in[4];
  const float* bk = (const float*)d_in[5];
  const float* Wv = (const float*)d_in[6];
  const float* bv = (const float*)d_in[7];
  const float* Wo = (const float*)d_in[8];
  const int* start_pos = (const int*)d_in[9];
  float* out = (float*)d_out;

  unsigned short* ws = (unsigned short*)d_ws;
  size_t off = 0;
  unsigned short* xb  = ws + off; off += (size_t)8192 * 2048;
  unsigned short* Wt  = ws + off; off += (size_t)3072 * 2048;
  unsigned short* Wot = ws + off; off += (size_t)2048 * 2048;
  unsigned short* Qb  = ws + off; off += (size_t)BATCH * NQH  * S_LEN * HDIM;
  unsigned short* Kb  = ws + off; off += (size_t)BATCH * NKVH * S_LEN * HDIM;
  unsigned short* Vtb = ws + off; off += (size_t)BATCH * NKVH * S_LEN * HDIM;
  unsigned short* Ob  = ws + off; off += (size_t)8192 * 2048;

  k_convert_x<<<2048, 256, 0, stream>>>(x, xb, 8192 * 2048 / 4);
  k_transpose_all<<<10240, 256, 0, stream>>>(Wq, Wk, Wv, Wo, Wt, Wot);

  k_gemm_q<<<dim3(256), 512, 0, stream>>>(xb, Wt, bq, Qb);
  k_gemm_kv<<<dim3(256), 512, 0, stream>>>(xb, Wt + (size_t)2048 * 2048, bk, bv, Kb, Vtb);

  k_ropeK<<<512, 256, 0, stream>>>(Kb, fc, start_pos, BATCH * NKVH * S_LEN * 64);

  k_flash2<<<dim3(512), 512, 0, stream>>>(Qb, Kb, Vtb, Ob, fc, start_pos);

  k_gemm_out256<<<dim3(256), 512, 0, stream>>>(Ob, Wot, out);
}

// Round 15
// 426.020 us; speedup vs baseline: 1.4890x; 1.4890x over previous
//
#include <hip/hip_runtime.h>
#include <stdint.h>

// ---------- common ----------
typedef __attribute__((ext_vector_type(8))) short bf16x8;
typedef __attribute__((ext_vector_type(4))) float f32x4;
typedef __attribute__((ext_vector_type(16))) float f32x16;

#define S_LEN 2048
#define D_MODEL 2048
#define NQH 16
#define NKVH 4
#define HDIM 128
#define BATCH 4

__device__ __forceinline__ float bf2f(unsigned short s) {
  union { unsigned u; float f; } v; v.u = ((unsigned)s) << 16; return v.f;
}
__device__ __forceinline__ unsigned short f2bf(float f) {
  union { float f; unsigned u; } v; v.f = f;
  unsigned r = v.u + 0x7FFFu + ((v.u >> 16) & 1u);
  return (unsigned short)(r >> 16);
}
__device__ __forceinline__ f32x4 fzero() {
  f32x4 v; v[0]=0.f; v[1]=0.f; v[2]=0.f; v[3]=0.f; return v;
}
__device__ __forceinline__ void async16(const void* g, void* l) {
  __builtin_amdgcn_global_load_lds(
      (const __attribute__((address_space(1))) unsigned int*)g,
      (__attribute__((address_space(3))) unsigned int*)l, 16, 0, 0);
}
__device__ __forceinline__ unsigned cvtpk(float lo, float hi) {
  unsigned r;
  asm("v_cvt_pk_bf16_f32 %0, %1, %2" : "=v"(r) : "v"(lo), "v"(hi));
  return r;
}

// ---------- fp32 -> bf16 bulk convert (x) ----------
__global__ void k_convert_x(const float* __restrict__ x, unsigned short* __restrict__ xb, int n4) {
  int stride = gridDim.x * blockDim.x;
  for (int i = blockIdx.x * blockDim.x + threadIdx.x; i < n4; i += stride) {
    float4 v = ((const float4*)x)[i];
    ushort4 o;
    o.x = f2bf(v.x); o.y = f2bf(v.y); o.z = f2bf(v.z); o.w = f2bf(v.w);
    ((ushort4*)xb)[i] = o;
  }
}

// ---------- all 4 weight transposes in one launch ----------
__global__ void k_transpose_all(const float* __restrict__ Wq, const float* __restrict__ Wk,
                                const float* __restrict__ Wv, const float* __restrict__ Wo,
                                unsigned short* __restrict__ Wt, unsigned short* __restrict__ Wot) {
  __shared__ float tile[32][33];
  int bid = blockIdx.x;
  const float* W; unsigned short* D; int N, nx;
  if (bid < 4096)      { W = Wq; D = Wt;                          N = 2048; nx = 64; }
  else if (bid < 5120) { W = Wk; D = Wt + (size_t)2048 * 2048;    N = 512;  nx = 16; bid -= 4096; }
  else if (bid < 6144) { W = Wv; D = Wt + (size_t)2560 * 2048;    N = 512;  nx = 16; bid -= 5120; }
  else                 { W = Wo; D = Wot;                         N = 2048; nx = 64; bid -= 6144; }
  int tx = threadIdx.x & 31, ty = threadIdx.x >> 5;
  int n0 = (bid % nx) * 32, k0 = (bid / nx) * 32;
  #pragma unroll
  for (int i = 0; i < 4; ++i)
    tile[ty + i*8][tx] = W[(size_t)(k0 + ty + i*8) * N + n0 + tx];
  __syncthreads();
  #pragma unroll
  for (int i = 0; i < 4; ++i)
    D[(size_t)(n0 + ty + i*8) * 2048 + k0 + tx] = f2bf(tile[tx][ty + i*8]);
}

// ---------- RoPE on K only (Q is roped inside flash) ----------
__global__ void k_ropeK(unsigned short* __restrict__ Kb, const float* __restrict__ fc,
                        const int* __restrict__ start_pos, int total) {
  int sp = start_pos[0];
  int stride = gridDim.x * blockDim.x;
  for (int i = blockIdx.x * blockDim.x + threadIdx.x; i < total; i += stride) {
    int d2 = i & 63;
    int s = (i >> 6) & (S_LEN - 1);
    unsigned v = ((unsigned*)Kb)[i];
    float x0 = bf2f((unsigned short)(v & 0xFFFFu));
    float x1 = bf2f((unsigned short)(v >> 16));
    float c  = fc[((size_t)(sp + s) * 64 + d2) * 2];
    float sn = fc[((size_t)(sp + s) * 64 + d2) * 2 + 1];
    float y0 = x0 * c - x1 * sn;
    float y1 = x0 * sn + x1 * c;
    ((unsigned*)Kb)[i] = (unsigned)f2bf(y0) | ((unsigned)f2bf(y1) << 16);
  }
}

#define BARRIER() __builtin_amdgcn_s_barrier()
#define LGKM0()  do { asm volatile("s_waitcnt lgkmcnt(0)" ::: "memory"); \
                      __builtin_amdgcn_sched_barrier(0); } while (0)
#define VMCNT6() asm volatile("s_waitcnt vmcnt(6)" ::: "memory")
#define VMCNT4() asm volatile("s_waitcnt vmcnt(4)" ::: "memory")
#define VMCNT0() asm volatile("s_waitcnt vmcnt(0)" ::: "memory")

__device__ __forceinline__ bf16x8 ldsrd(const unsigned short* L, int row, int kk, int g) {
  int Xs = (kk * 64 + g * 16) ^ ((row & 7) << 4);
  return *(const bf16x8*)&L[row * 64 + (Xs >> 1)];
}
// wave-cooperative: write 8 rows at rowbase (multiple of 8) of [256][64] tile
__device__ __forceinline__ void stage8(const unsigned short* __restrict__ G, int gbase,
                                       int k0, unsigned short* lds, int rowbase, int lane) {
  int row = rowbase + (lane >> 3);
  int col8 = (lane & 7) ^ ((lane >> 3) & 7);
  async16(G + (size_t)(gbase + row) * 2048 + k0 + col8 * 8, lds + rowbase * 64 + lane * 8);
}

const float SCL2E_H = 0.08838834764831845f * 1.4426950408889634f;  // scale * log2(e)

// ============ Q GEMM: 256x256 4-phase, grid 32x8=256 ============
__global__ __launch_bounds__(512, 2) void k_gemm_q(
    const unsigned short* __restrict__ A, const unsigned short* __restrict__ Bt,
    const float* __restrict__ bq, unsigned short* __restrict__ Qo)
{
  __shared__ __align__(16) unsigned short Abuf[2][256 * 64];
  __shared__ __align__(16) unsigned short Bbuf[2][256 * 64];
  const int NT = 32, NXT = 8;
  const int tid = threadIdx.x, lane = tid & 63, w = tid >> 6;
  const int lr = lane & 15, g = lane >> 4;
  const int wm = w >> 2, wn = w & 3;

  int nwg = NXT * 32;
  int cpx = nwg >> 3;
  int bid = blockIdx.x;
  int swz = (bid & 7) * cpx + (bid >> 3);
  const int by = swz / NXT, bx = swz % NXT;
  const int mbase = by * 256, nbase = bx * 256;

  #define ST_AQ02(tt) if ((tt) < NT) { unsigned short* L = Abuf[(tt) & 1]; int k0 = (tt) * 64; \
    _Pragma("unroll") for (int it = 0; it < 2; ++it) { int sub = it * 8 + w; \
      stage8(A, mbase, k0, L, (sub >> 3) * 128 + (sub & 7) * 8, lane); } }
  #define ST_AQ13(tt) if ((tt) < NT) { unsigned short* L = Abuf[(tt) & 1]; int k0 = (tt) * 64; \
    _Pragma("unroll") for (int it = 0; it < 2; ++it) { int sub = it * 8 + w; \
      stage8(A, mbase, k0, L, 64 + (sub >> 3) * 128 + (sub & 7) * 8, lane); } }
  #define ST_BS0(tt) if ((tt) < NT) { unsigned short* L = Bbuf[(tt) & 1]; int k0 = (tt) * 64; \
    _Pragma("unroll") for (int it = 0; it < 2; ++it) { int sub = it * 8 + w; \
      stage8(Bt, nbase, k0, L, (sub >> 2) * 64 + (sub & 3) * 8, lane); } }
  #define ST_BS1(tt) if ((tt) < NT) { unsigned short* L = Bbuf[(tt) & 1]; int k0 = (tt) * 64; \
    _Pragma("unroll") for (int it = 0; it < 2; ++it) { int sub = it * 8 + w; \
      stage8(Bt, nbase, k0, L, 32 + (sub >> 2) * 64 + (sub & 3) * 8, lane); } }

  f32x4 acc[8][4];
  #pragma unroll
  for (int m = 0; m < 8; ++m)
    #pragma unroll
    for (int n = 0; n < 4; ++n) acc[m][n] = fzero();

  ST_AQ02(0); ST_AQ13(0); ST_BS0(0); ST_BS1(0);
  ST_AQ02(1); ST_BS1(1);
  VMCNT4();
  BARRIER();

  bf16x8 a[2][4], b[2][2];

  for (int t = 0; t < NT; ++t) {
    const unsigned short* Al = Abuf[t & 1];
    const unsigned short* Bl = Bbuf[t & 1];

    #pragma unroll
    for (int kk = 0; kk < 2; ++kk) {
      #pragma unroll
      for (int m = 0; m < 4; ++m) a[kk][m] = ldsrd(Al, wm * 128 + m * 16 + lr, kk, g);
      #pragma unroll
      for (int n = 0; n < 2; ++n) b[kk][n] = ldsrd(Bl, wn * 64 + n * 16 + lr, kk, g);
    }
    ST_AQ13(t + 1);
    BARRIER(); LGKM0();
    __builtin_amdgcn_s_setprio(1);
    #pragma unroll
    for (int kk = 0; kk < 2; ++kk)
      #pragma unroll
      for (int m = 0; m < 4; ++m)
        #pragma unroll
        for (int n = 0; n < 2; ++n)
          acc[m][n] = __builtin_amdgcn_mfma_f32_16x16x32_bf16(a[kk][m], b[kk][n], acc[m][n], 0, 0, 0);
    __builtin_amdgcn_s_setprio(0);
    BARRIER();

    #pragma unroll
    for (int kk = 0; kk < 2; ++kk)
      #pragma unroll
      for (int n = 0; n < 2; ++n) b[kk][n] = ldsrd(Bl, wn * 64 + (2 + n) * 16 + lr, kk, g);
    ST_BS0(t + 1);
    BARRIER(); LGKM0();
    __builtin_amdgcn_s_setprio(1);
    #pragma unroll
    for (int kk = 0; kk < 2; ++kk)
      #pragma unroll
      for (int m = 0; m < 4; ++m)
        #pragma unroll
        for (int n = 0; n < 2; ++n)
          acc[m][2 + n] = __builtin_amdgcn_mfma_f32_16x16x32_bf16(a[kk][m], b[kk][n], acc[m][2 + n], 0, 0, 0);
    __builtin_amdgcn_s_setprio(0);
    BARRIER();

    #pragma unroll
    for (int kk = 0; kk < 2; ++kk)
      #pragma unroll
      for (int m = 0; m < 4; ++m) a[kk][m] = ldsrd(Al, wm * 128 + 64 + m * 16 + lr, kk, g);
    ST_AQ02(t + 2);
    BARRIER(); LGKM0();
    __builtin_amdgcn_s_setprio(1);
    #pragma unroll
    for (int kk = 0; kk < 2; ++kk)
      #pragma unroll
      for (int m = 0; m < 4; ++m)
        #pragma unroll
        for (int n = 0; n < 2; ++n)
          acc[4 + m][2 + n] = __builtin_amdgcn_mfma_f32_16x16x32_bf16(a[kk][m], b[kk][n], acc[4 + m][2 + n], 0, 0, 0);
    __builtin_amdgcn_s_setprio(0);
    BARRIER();

    #pragma unroll
    for (int kk = 0; kk < 2; ++kk)
      #pragma unroll
      for (int n = 0; n < 2; ++n) b[kk][n] = ldsrd(Bl, wn * 64 + n * 16 + lr, kk, g);
    ST_BS1(t + 2);
    VMCNT4();
    BARRIER(); LGKM0();
    __builtin_amdgcn_s_setprio(1);
    #pragma unroll
    for (int kk = 0; kk < 2; ++kk)
      #pragma unroll
      for (int m = 0; m < 4; ++m)
        #pragma unroll
        for (int n = 0; n < 2; ++n)
          acc[4 + m][n] = __builtin_amdgcn_mfma_f32_16x16x32_bf16(a[kk][m], b[kk][n], acc[4 + m][n], 0, 0, 0);
    __builtin_amdgcn_s_setprio(0);
    BARRIER();
  }

  #pragma unroll
  for (int n = 0; n < 4; ++n) {
    const int ng = nbase + wn * 64 + n * 16 + lr;
    const int hh = ng >> 7, dd = ng & 127;
    const float bias = bq[ng];
    #pragma unroll
    for (int m = 0; m < 8; ++m)
      #pragma unroll
      for (int i = 0; i < 4; ++i) {
        int mg = mbase + wm * 128 + m * 16 + g * 4 + i;
        int bb = mg >> 11, s = mg & 2047;
        float val = (acc[m][n][i] + bias) * SCL2E_H;
        Qo[((size_t)(bb * NQH + hh) * S_LEN + s) * HDIM + dd] = f2bf(val);
      }
  }
  #undef ST_AQ02
  #undef ST_AQ13
  #undef ST_BS0
  #undef ST_BS1
}

// ============ KV GEMM: 256x128 2-phase triple-buffered, N=1024, grid 32x8=256 ============
__global__ __launch_bounds__(512, 2) void k_gemm_kv(
    const unsigned short* __restrict__ A, const unsigned short* __restrict__ Bt,
    const float* __restrict__ bk, const float* __restrict__ bv,
    unsigned short* __restrict__ Ko, unsigned short* __restrict__ Vto)
{
  __shared__ __align__(16) unsigned short Ab[3][256 * 64];
  __shared__ __align__(16) unsigned short Bb[3][128 * 64];
  const int NT = 32, NXT = 8;
  const int tid = threadIdx.x, lane = tid & 63, w = tid >> 6;
  const int lr = lane & 15, g = lane >> 4;
  const int wm = w >> 1, wn = w & 1;

  int nwg = NXT * 32;
  int cpx = nwg >> 3;
  int bid = blockIdx.x;
  int swz = (bid & 7) * cpx + (bid >> 3);
  const int by = swz / NXT, bx = swz % NXT;
  const int mbase = by * 256, nbase = bx * 128;

  #define ST_A(tt) { unsigned short* L = Ab[(tt) % 3]; int k0 = (tt) * 64; \
    _Pragma("unroll") for (int it = 0; it < 4; ++it) { int c = tid + it * 512; \
      int row = c >> 3, col8 = (c & 7) ^ (row & 7); \
      async16(A + (size_t)(mbase + row) * 2048 + k0 + col8 * 8, L + c * 8); } }
  #define ST_B(tt) { unsigned short* L = Bb[(tt) % 3]; int k0 = (tt) * 64; \
    _Pragma("unroll") for (int it = 0; it < 2; ++it) { int c = tid + it * 512; \
      int row = c >> 3, col8 = (c & 7) ^ (row & 7); \
      async16(Bt + (size_t)(nbase + row) * 2048 + k0 + col8 * 8, L + c * 8); } }

  f32x4 acc[4][4];
  #pragma unroll
  for (int m = 0; m < 4; ++m)
    #pragma unroll
    for (int n = 0; n < 4; ++n) acc[m][n] = fzero();

  ST_A(0); ST_B(0); ST_A(1); ST_B(1);
  VMCNT6();
  BARRIER();

  for (int t = 0; t < NT; ++t) {
    const unsigned short* Al = Ab[t % 3];
    const unsigned short* Bl = Bb[t % 3];
    bf16x8 a[2][4], b[2][2];

    #pragma unroll
    for (int kk = 0; kk < 2; ++kk) {
      #pragma unroll
      for (int m = 0; m < 4; ++m) a[kk][m] = ldsrd(Al, wm * 64 + m * 16 + lr, kk, g);
      #pragma unroll
      for (int n = 0; n < 2; ++n) b[kk][n] = ldsrd(Bl, wn * 64 + n * 16 + lr, kk, g);
    }
    if (t + 2 < NT) ST_A(t + 2);
    BARRIER(); LGKM0();
    __builtin_amdgcn_s_setprio(1);
    #pragma unroll
    for (int kk = 0; kk < 2; ++kk)
      #pragma unroll
      for (int m = 0; m < 4; ++m)
        #pragma unroll
        for (int n = 0; n < 2; ++n)
          acc[m][n] = __builtin_amdgcn_mfma_f32_16x16x32_bf16(a[kk][m], b[kk][n], acc[m][n], 0, 0, 0);
    __builtin_amdgcn_s_setprio(0);
    BARRIER();

    #pragma unroll
    for (int kk = 0; kk < 2; ++kk)
      #pragma unroll
      for (int n = 0; n < 2; ++n) b[kk][n] = ldsrd(Bl, wn * 64 + (2 + n) * 16 + lr, kk, g);
    if (t + 2 < NT) { ST_B(t + 2); VMCNT6(); } else { VMCNT0(); }
    BARRIER(); LGKM0();
    __builtin_amdgcn_s_setprio(1);
    #pragma unroll
    for (int kk = 0; kk < 2; ++kk)
      #pragma unroll
      for (int m = 0; m < 4; ++m)
        #pragma unroll
        for (int n = 0; n < 2; ++n)
          acc[m][2 + n] = __builtin_amdgcn_mfma_f32_16x16x32_bf16(a[kk][m], b[kk][n], acc[m][2 + n], 0, 0, 0);
    __builtin_amdgcn_s_setprio(0);
    BARRIER();
  }

  #pragma unroll
  for (int n = 0; n < 4; ++n) {
    const int ng = nbase + wn * 64 + n * 16 + lr;        // 0..1023
    const bool isK = (ng < 512);
    const int nn = isK ? ng : ng - 512;
    const int hh = nn >> 7, dd = nn & 127;
    const float bias = isK ? bk[nn] : bv[nn];
    #pragma unroll
    for (int m = 0; m < 4; ++m)
      #pragma unroll
      for (int i = 0; i < 4; ++i) {
        int mg = mbase + wm * 64 + m * 16 + g * 4 + i;
        int bb = mg >> 11, s = mg & 2047;
        float val = acc[m][n][i] + bias;
        if (isK) {
          Ko[((size_t)(bb * NKVH + hh) * S_LEN + s) * HDIM + dd] = f2bf(val);
        } else {
          Vto[((size_t)(bb * NKVH + hh) * HDIM + dd) * S_LEN + s] = f2bf(val);
        }
      }
  }
  #undef ST_A
  #undef ST_B
}

// ============ OUT GEMM: 256x256 4-phase, grid 256 ============
__global__ __launch_bounds__(512, 2) void k_gemm_out256(
    const unsigned short* __restrict__ A, const unsigned short* __restrict__ Bt,
    float* __restrict__ Cf)
{
  __shared__ __align__(16) unsigned short Abuf[2][256 * 64];
  __shared__ __align__(16) unsigned short Bbuf[2][256 * 64];
  const int NT = 32, NXT = 8;
  const int tid = threadIdx.x, lane = tid & 63, w = tid >> 6;
  const int lr = lane & 15, g = lane >> 4;
  const int wm = w >> 2, wn = w & 3;

  int nwg = NXT * 32;
  int cpx = nwg >> 3;
  int bid = blockIdx.x;
  int swz = (bid & 7) * cpx + (bid >> 3);
  const int by = swz / NXT, bx = swz % NXT;
  const int mbase = by * 256, nbase = bx * 256;

  #define ST_AQ02(tt) if ((tt) < NT) { unsigned short* L = Abuf[(tt) & 1]; int k0 = (tt) * 64; \
    _Pragma("unroll") for (int it = 0; it < 2; ++it) { int sub = it * 8 + w; \
      stage8(A, mbase, k0, L, (sub >> 3) * 128 + (sub & 7) * 8, lane); } }
  #define ST_AQ13(tt) if ((tt) < NT) { unsigned short* L = Abuf[(tt) & 1]; int k0 = (tt) * 64; \
    _Pragma("unroll") for (int it = 0; it < 2; ++it) { int sub = it * 8 + w; \
      stage8(A, mbase, k0, L, 64 + (sub >> 3) * 128 + (sub & 7) * 8, lane); } }
  #define ST_BS0(tt) if ((tt) < NT) { unsigned short* L = Bbuf[(tt) & 1]; int k0 = (tt) * 64; \
    _Pragma("unroll") for (int it = 0; it < 2; ++it) { int sub = it * 8 + w; \
      stage8(Bt, nbase, k0, L, (sub >> 2) * 64 + (sub & 3) * 8, lane); } }
  #define ST_BS1(tt) if ((tt) < NT) { unsigned short* L = Bbuf[(tt) & 1]; int k0 = (tt) * 64; \
    _Pragma("unroll") for (int it = 0; it < 2; ++it) { int sub = it * 8 + w; \
      stage8(Bt, nbase, k0, L, 32 + (sub >> 2) * 64 + (sub & 3) * 8, lane); } }

  f32x4 acc[8][4];
  #pragma unroll
  for (int m = 0; m < 8; ++m)
    #pragma unroll
    for (int n = 0; n < 4; ++n) acc[m][n] = fzero();

  ST_AQ02(0); ST_AQ13(0); ST_BS0(0); ST_BS1(0);
  ST_AQ02(1); ST_BS1(1);
  VMCNT4();
  BARRIER();

  bf16x8 a[2][4], b[2][2];

  for (int t = 0; t < NT; ++t) {
    const unsigned short* Al = Abuf[t & 1];
    const unsigned short* Bl = Bbuf[t & 1];

    #pragma unroll
    for (int kk = 0; kk < 2; ++kk) {
      #pragma unroll
      for (int m = 0; m < 4; ++m) a[kk][m] = ldsrd(Al, wm * 128 + m * 16 + lr, kk, g);
      #pragma unroll
      for (int n = 0; n < 2; ++n) b[kk][n] = ldsrd(Bl, wn * 64 + n * 16 + lr, kk, g);
    }
    ST_AQ13(t + 1);
    BARRIER(); LGKM0();
    __builtin_amdgcn_s_setprio(1);
    #pragma unroll
    for (int kk = 0; kk < 2; ++kk)
      #pragma unroll
      for (int m = 0; m < 4; ++m)
        #pragma unroll
        for (int n = 0; n < 2; ++n)
          acc[m][n] = __builtin_amdgcn_mfma_f32_16x16x32_bf16(a[kk][m], b[kk][n], acc[m][n], 0, 0, 0);
    __builtin_amdgcn_s_setprio(0);
    BARRIER();

    #pragma unroll
    for (int kk = 0; kk < 2; ++kk)
      #pragma unroll
      for (int n = 0; n < 2; ++n) b[kk][n] = ldsrd(Bl, wn * 64 + (2 + n) * 16 + lr, kk, g);
    ST_BS0(t + 1);
    BARRIER(); LGKM0();
    __builtin_amdgcn_s_setprio(1);
    #pragma unroll
    for (int kk = 0; kk < 2; ++kk)
      #pragma unroll
      for (int m = 0; m < 4; ++m)
        #pragma unroll
        for (int n = 0; n < 2; ++n)
          acc[m][2 + n] = __builtin_amdgcn_mfma_f32_16x16x32_bf16(a[kk][m], b[kk][n], acc[m][2 + n], 0, 0, 0);
    __builtin_amdgcn_s_setprio(0);
    BARRIER();

    #pragma unroll
    for (int kk = 0; kk < 2; ++kk)
      #pragma unroll
      for (int m = 0; m < 4; ++m) a[kk][m] = ldsrd(Al, wm * 128 + 64 + m * 16 + lr, kk, g);
    ST_AQ02(t + 2);
    BARRIER(); LGKM0();
    __builtin_amdgcn_s_setprio(1);
    #pragma unroll
    for (int kk = 0; kk < 2; ++kk)
      #pragma unroll
      for (int m = 0; m < 4; ++m)
        #pragma unroll
        for (int n = 0; n < 2; ++n)
          acc[4 + m][2 + n] = __builtin_amdgcn_mfma_f32_16x16x32_bf16(a[kk][m], b[kk][n], acc[4 + m][2 + n], 0, 0, 0);
    __builtin_amdgcn_s_setprio(0);
    BARRIER();

    #pragma unroll
    for (int kk = 0; kk < 2; ++kk)
      #pragma unroll
      for (int n = 0; n < 2; ++n) b[kk][n] = ldsrd(Bl, wn * 64 + n * 16 + lr, kk, g);
    ST_BS1(t + 2);
    VMCNT4();
    BARRIER(); LGKM0();
    __builtin_amdgcn_s_setprio(1);
    #pragma unroll
    for (int kk = 0; kk < 2; ++kk)
      #pragma unroll
      for (int m = 0; m < 4; ++m)
        #pragma unroll
        for (int n = 0; n < 2; ++n)
          acc[4 + m][n] = __builtin_amdgcn_mfma_f32_16x16x32_bf16(a[kk][m], b[kk][n], acc[4 + m][n], 0, 0, 0);
    __builtin_amdgcn_s_setprio(0);
    BARRIER();
  }

  #pragma unroll
  for (int m = 0; m < 8; ++m)
    #pragma unroll
    for (int n = 0; n < 4; ++n)
      #pragma unroll
      for (int i = 0; i < 4; ++i) {
        int mg = mbase + wm * 128 + m * 16 + g * 4 + i;
        int ng = nbase + wn * 64 + n * 16 + lr;
        Cf[(size_t)mg * 2048 + ng] = acc[m][n][i];
      }
  #undef ST_AQ02
  #undef ST_AQ13
  #undef ST_BS0
  #undef ST_BS1
}

// ---------- flash v10: 4 waves, K dbuf + V single (48KB LDS -> 3 blocks/CU), split-stage ----------
// Q un-roped, pre-scaled by scale*log2e. K roped. Vt [BKV][128][2048].
// block = (bh, tp in 0..7); q-tiles {tp, 15-tp} of 128 rows; diag-only mask.
__global__ __launch_bounds__(256, 3) void k_flash2(
    const unsigned short* __restrict__ Q, const unsigned short* __restrict__ K,
    const unsigned short* __restrict__ Vt, unsigned short* __restrict__ O,
    const float* __restrict__ fc, const int* __restrict__ start_pos)
{
  __shared__ __align__(16) unsigned short SH[24576];  // 48KB: K dbuf 2x16KB | V 16KB

  const int tid = threadIdx.x;
  const int lane = tid & 63;
  const int w = tid >> 6;        // 0..3
  const int ql = lane & 31;
  const int hi = lane >> 5;

  const int bh = blockIdx.x >> 3;
  const int tp = blockIdx.x & 7;
  const int b = bh >> 4, h = bh & 15;
  const int kh = h >> 2;
  const int sp = start_pos[0];

  const unsigned short* Qbase = Q + (size_t)(b * NQH + h) * S_LEN * HDIM;
  const unsigned short* Kbase = K + (size_t)(b * NKVH + kh) * S_LEN * HDIM;
  const unsigned short* Vtb   = Vt + (size_t)(b * NKVH + kh) * HDIM * S_LEN;

  // stage K tile jj (64 rows x 128) into K buf jj&1 (4 loads/thread)
  #define STAGEK(jj) { unsigned short* Kd = SH + ((jj) & 1) * 8192; \
    _Pragma("unroll") for (int it = 0; it < 4; ++it) { \
      int c = tid + it * 256; int row = c >> 4, col = c & 15; \
      int lcol = (col & 8) | ((col ^ (row & 7)) & 7); \
      async16(Kbase + (size_t)((jj) * 64 + row) * HDIM + lcol * 8, Kd + c * 8); } }
  // stage V tile jj (128 d-rows x 64) into single V buf (4 loads/thread)
  #define STAGEV(jj) { unsigned short* Vd = SH + 16384; \
    _Pragma("unroll") for (int it = 0; it < 4; ++it) { \
      int c = tid + it * 256; int row = c >> 3, col = c & 7; \
      int lcol = col ^ (row & 7); \
      async16(Vtb + (size_t)row * S_LEN + (jj) * 64 + lcol * 8, Vd + c * 8); } }

  #pragma unroll 1
  for (int half = 0; half < 2; ++half) {
    const int t = half ? (15 - tp) : tp;
    const int nkv = 2 * t + 2;
    const int qg = t * 128 + w * 32 + ql;
    const int jd = 2 * t + (w >> 1);   // wave's diagonal iteration
    const int ql2 = (w & 1) * 32 + ql; // q row within the diagonal 64-block

    __syncthreads();  // protect LDS reuse across halves

    // Q load + in-register RoPE
    bf16x8 qf[8];
    {
      const unsigned short* qp = Qbase + (size_t)qg * HDIM;
      const float* fcrow = fc + (size_t)(sp + qg) * 128;
      #pragma unroll
      for (int dd = 0; dd < 8; ++dd) {
        bf16x8 raw = *(const bf16x8*)(qp + dd * 16 + hi * 8);
        int d2b = (dd * 16 + hi * 8) >> 1;
        union { unsigned u[4]; bf16x8 v; } out;
        #pragma unroll
        for (int u2 = 0; u2 < 4; ++u2) {
          float x0 = bf2f((unsigned short)raw[2 * u2]);
          float x1 = bf2f((unsigned short)raw[2 * u2 + 1]);
          float2 cs = *(const float2*)&fcrow[(d2b + u2) * 2];
          out.u[u2] = cvtpk(x0 * cs.x - x1 * cs.y, x0 * cs.y + x1 * cs.x);
        }
        qf[dd] = out.v;
      }
    }

    float m_r = -1e30f, l_r = 0.f;
    f32x16 oA[4];
    #pragma unroll
    for (int db = 0; db < 4; ++db)
      #pragma unroll
      for (int r = 0; r < 16; ++r) oA[db][r] = 0.f;

    STAGEK(0);
    STAGEV(0);
    VMCNT0();
    BARRIER();

    for (int j = 0; j < nkv; ++j) {
      const unsigned short* Kl = SH + (j & 1) * 8192;
      const unsigned short* Vl = SH + 16384;
      const bool act = (j <= jd);
      const bool more = (j + 1 < nkv);

      if (more) STAGEK(j + 1);          // K(j+1) in flight during compute

      f32x16 p0, p1;
      bf16x8 pb[4];
      if (act) {
        #pragma unroll
        for (int r = 0; r < 16; ++r) { p0[r] = 0.f; p1[r] = 0.f; }
        __builtin_amdgcn_s_setprio(1);
        #pragma unroll
        for (int dd = 0; dd < 8; ++dd) {
          const int off = (((dd * 32 + hi * 16) ^ ((ql & 7) << 4)) >> 1);
          bf16x8 a0 = *(const bf16x8*)&Kl[ql * 128 + off];
          bf16x8 a1 = *(const bf16x8*)&Kl[(32 + ql) * 128 + off];
          p0 = __builtin_amdgcn_mfma_f32_32x32x16_bf16(a0, qf[dd], p0, 0, 0, 0);
          p1 = __builtin_amdgcn_mfma_f32_32x32x16_bf16(a1, qf[dd], p1, 0, 0, 0);
        }
        __builtin_amdgcn_s_setprio(0);

        if (j == jd) {  // diagonal-only causal mask
          #pragma unroll
          for (int r = 0; r < 16; ++r) {
            const int klh = (r & 3) + 8 * (r >> 2) + 4 * hi;
            if (klh > ql2) p0[r] = -1e30f;
            if (klh + 32 > ql2) p1[r] = -1e30f;
          }
        }

        float pm = -1e30f;
        #pragma unroll
        for (int r = 0; r < 16; ++r) pm = fmaxf(pm, fmaxf(p0[r], p1[r]));
        pm = fmaxf(pm, __shfl_xor(pm, 32));
        if (!__all(pm - m_r <= 8.0f)) {
          const float mn = fmaxf(m_r, pm);
          const float corr = exp2f(m_r - mn);
          m_r = mn;
          l_r *= corr;
          #pragma unroll
          for (int db = 0; db < 4; ++db)
            #pragma unroll
            for (int r = 0; r < 16; ++r) oA[db][r] *= corr;
        }
        float rs = 0.f;
        #pragma unroll
        for (int r = 0; r < 16; ++r) {
          p0[r] = exp2f(p0[r] - m_r);
          p1[r] = exp2f(p1[r] - m_r);
          rs += p0[r] + p1[r];
        }
        rs += __shfl_xor(rs, 32);
        l_r += rs;

        unsigned Wv[8], W2v[8];
        #pragma unroll
        for (int d = 0; d < 4; ++d) {
          Wv[d]      = cvtpk(p0[4*d],     p0[4*d + 1]);
          W2v[d]     = cvtpk(p0[4*d + 2], p0[4*d + 3]);
          Wv[4 + d]  = cvtpk(p1[4*d],     p1[4*d + 1]);
          W2v[4 + d] = cvtpk(p1[4*d + 2], p1[4*d + 3]);
        }
        #pragma unroll
        for (int kt = 0; kt < 2; ++kt) {
          #pragma unroll
          for (int s = 0; s < 2; ++s) {
            unsigned ownW   = hi ? Wv[kt*4 + 2*s + 1]  : Wv[kt*4 + 2*s];
            unsigned sendW  = hi ? Wv[kt*4 + 2*s]      : Wv[kt*4 + 2*s + 1];
            unsigned recvW  = (unsigned)__shfl_xor((int)sendW, 32);
            unsigned ownW2  = hi ? W2v[kt*4 + 2*s + 1] : W2v[kt*4 + 2*s];
            unsigned sendW2 = hi ? W2v[kt*4 + 2*s]     : W2v[kt*4 + 2*s + 1];
            unsigned recvW2 = (unsigned)__shfl_xor((int)sendW2, 32);
            union { unsigned u[4]; bf16x8 v; } pk;
            pk.u[0] = hi ? recvW  : ownW;
            pk.u[1] = hi ? recvW2 : ownW2;
            pk.u[2] = hi ? ownW   : recvW;
            pk.u[3] = hi ? ownW2  : recvW2;
            pb[kt*2 + s] = pk.v;
          }
        }
      }

      // V(j) landed? (issued end of prev iter / prologue). FIFO: retire it.
      if (more) { VMCNT4(); } else { VMCNT0(); }
      BARRIER();

      if (act) {
        __builtin_amdgcn_s_setprio(1);
        #pragma unroll
        for (int ks = 0; ks < 4; ++ks) {
          #pragma unroll
          for (int db = 0; db < 4; ++db) {
            const int off = (((ks * 32 + hi * 16) ^ ((ql & 7) << 4)) >> 1);
            bf16x8 av = *(const bf16x8*)&Vl[(db * 32 + ql) * 64 + off];
            oA[db] = __builtin_amdgcn_mfma_f32_32x32x16_bf16(av, pb[ks], oA[db], 0, 0, 0);
          }
        }
        __builtin_amdgcn_s_setprio(0);
      }
      BARRIER();                        // all waves done reading V(j)

      if (more) {
        STAGEV(j + 1);                  // overwrite V buf
        VMCNT4();                       // retire K(j+1); V(j+1) stays in flight
        BARRIER();
      }
    }

    // epilogue: O^T -> LDS (transpose, swizzled) -> coalesced global (128 rows x 256B = 32KB)
    {
      const float invl = 1.f / l_r;
      const int qloc = w * 32 + ql;
      #pragma unroll
      for (int db = 0; db < 4; ++db)
        #pragma unroll
        for (int g4 = 0; g4 < 4; ++g4) {
          unsigned lo  = cvtpk(oA[db][g4*4 + 0] * invl, oA[db][g4*4 + 1] * invl);
          unsigned hi2 = cvtpk(oA[db][g4*4 + 2] * invl, oA[db][g4*4 + 3] * invl);
          int byteoff = qloc * 256 + ((db * 64 + g4 * 16 + hi * 8) ^ ((qloc & 7) << 4));
          *(uint2*)((char*)SH + byteoff) = make_uint2(lo, hi2);
        }
    }
    __syncthreads();
    {
      const int q2 = tid >> 1, hf = tid & 1;
      unsigned short* orow = O + ((size_t)(b * S_LEN + t * 128 + q2)) * D_MODEL + h * HDIM + hf * 64;
      #pragma unroll
      for (int u = 0; u < 8; ++u) {
        int byteoff = q2 * 256 + ((hf * 128 + u * 16) ^ ((q2 & 7) << 4));
        bf16x8 v = *(const bf16x8*)((const char*)SH + byteoff);
        *(bf16x8*)(orow + u * 8) = v;
      }
    }
  }
  #undef STAGEK
  #undef STAGEV
}

// ---------- launch ----------
extern "C" void kernel_launch(void* const* d_in, const int* in_sizes, int n_in,
                              void* d_out, int out_size, void* d_ws, size_t ws_size,
                              hipStream_t stream) {
  (void)in_sizes; (void)n_in; (void)out_size; (void)ws_size;
  const float* x  = (const float*)d_in[0];
  const float* fc = (const float*)d_in[1];
  const float* Wq = (const float*)d_in[2];
  const float* bq = (const float*)d_in[3];
  const float* Wk = (const float*)d_in[4];
  const float* bk = (const float*)d_in[5];
  const float* Wv = (const float*)d_in[6];
  const float* bv = (const float*)d_in[7];
  const float* Wo = (const float*)d_in[8];
  const int* start_pos = (const int*)d_in[9];
  float* out = (float*)d_out;

  unsigned short* ws = (unsigned short*)d_ws;
  size_t off = 0;
  unsigned short* xb  = ws + off; off += (size_t)8192 * 2048;
  unsigned short* Wt  = ws + off; off += (size_t)3072 * 2048;
  unsigned short* Wot = ws + off; off += (size_t)2048 * 2048;
  unsigned short* Qb  = ws + off; off += (size_t)BATCH * NQH  * S_LEN * HDIM;
  unsigned short* Kb  = ws + off; off += (size_t)BATCH * NKVH * S_LEN * HDIM;
  unsigned short* Vtb = ws + off; off += (size_t)BATCH * NKVH * S_LEN * HDIM;
  unsigned short* Ob  = ws + off; off += (size_t)8192 * 2048;

  k_convert_x<<<2048, 256, 0, stream>>>(x, xb, 8192 * 2048 / 4);
  k_transpose_all<<<10240, 256, 0, stream>>>(Wq, Wk, Wv, Wo, Wt, Wot);

  k_gemm_q<<<dim3(256), 512, 0, stream>>>(xb, Wt, bq, Qb);
  k_gemm_kv<<<dim3(256), 512, 0, stream>>>(xb, Wt + (size_t)2048 * 2048, bk, bv, Kb, Vtb);

  k_ropeK<<<512, 256, 0, stream>>>(Kb, fc, start_pos, BATCH * NKVH * S_LEN * 64);

  k_flash2<<<dim3(512), 256, 0, stream>>>(Qb, Kb, Vtb, Ob, fc, start_pos);

  k_gemm_out256<<<dim3(256), 512, 0, stream>>>(Ob, Wot, out);
}

// Round 16
// 336.926 us; speedup vs baseline: 1.8827x; 1.2644x over previous
//
#include <hip/hip_runtime.h>
#include <stdint.h>

// ---------- common ----------
typedef __attribute__((ext_vector_type(8))) short bf16x8;
typedef __attribute__((ext_vector_type(4))) float f32x4;
typedef __attribute__((ext_vector_type(16))) float f32x16;

#define S_LEN 2048
#define D_MODEL 2048
#define NQH 16
#define NKVH 4
#define HDIM 128
#define BATCH 4

__device__ __forceinline__ float bf2f(unsigned short s) {
  union { unsigned u; float f; } v; v.u = ((unsigned)s) << 16; return v.f;
}
__device__ __forceinline__ unsigned short f2bf(float f) {
  union { float f; unsigned u; } v; v.f = f;
  unsigned r = v.u + 0x7FFFu + ((v.u >> 16) & 1u);
  return (unsigned short)(r >> 16);
}
__device__ __forceinline__ f32x4 fzero() {
  f32x4 v; v[0]=0.f; v[1]=0.f; v[2]=0.f; v[3]=0.f; return v;
}
__device__ __forceinline__ void async16(const void* g, void* l) {
  __builtin_amdgcn_global_load_lds(
      (const __attribute__((address_space(1))) unsigned int*)g,
      (__attribute__((address_space(3))) unsigned int*)l, 16, 0, 0);
}
__device__ __forceinline__ unsigned cvtpk(float lo, float hi) {
  unsigned r;
  asm("v_cvt_pk_bf16_f32 %0, %1, %2" : "=v"(r) : "v"(lo), "v"(hi));
  return r;
}

// ---------- fp32 -> bf16 bulk convert (x) ----------
__global__ void k_convert_x(const float* __restrict__ x, unsigned short* __restrict__ xb, int n4) {
  int stride = gridDim.x * blockDim.x;
  for (int i = blockIdx.x * blockDim.x + threadIdx.x; i < n4; i += stride) {
    float4 v = ((const float4*)x)[i];
    ushort4 o;
    o.x = f2bf(v.x); o.y = f2bf(v.y); o.z = f2bf(v.z); o.w = f2bf(v.w);
    ((ushort4*)xb)[i] = o;
  }
}

// ---------- all 4 weight transposes in one launch ----------
__global__ void k_transpose_all(const float* __restrict__ Wq, const float* __restrict__ Wk,
                                const float* __restrict__ Wv, const float* __restrict__ Wo,
                                unsigned short* __restrict__ Wt, unsigned short* __restrict__ Wot) {
  __shared__ float tile[32][33];
  int bid = blockIdx.x;
  const float* W; unsigned short* D; int N, nx;
  if (bid < 4096)      { W = Wq; D = Wt;                          N = 2048; nx = 64; }
  else if (bid < 5120) { W = Wk; D = Wt + (size_t)2048 * 2048;    N = 512;  nx = 16; bid -= 4096; }
  else if (bid < 6144) { W = Wv; D = Wt + (size_t)2560 * 2048;    N = 512;  nx = 16; bid -= 5120; }
  else                 { W = Wo; D = Wot;                         N = 2048; nx = 64; bid -= 6144; }
  int tx = threadIdx.x & 31, ty = threadIdx.x >> 5;
  int n0 = (bid % nx) * 32, k0 = (bid / nx) * 32;
  #pragma unroll
  for (int i = 0; i < 4; ++i)
    tile[ty + i*8][tx] = W[(size_t)(k0 + ty + i*8) * N + n0 + tx];
  __syncthreads();
  #pragma unroll
  for (int i = 0; i < 4; ++i)
    D[(size_t)(n0 + ty + i*8) * 2048 + k0 + tx] = f2bf(tile[tx][ty + i*8]);
}

// ---------- RoPE on K only (Q is roped inside flash) ----------
__global__ void k_ropeK(unsigned short* __restrict__ Kb, const float* __restrict__ fc,
                        const int* __restrict__ start_pos, int total) {
  int sp = start_pos[0];
  int stride = gridDim.x * blockDim.x;
  for (int i = blockIdx.x * blockDim.x + threadIdx.x; i < total; i += stride) {
    int d2 = i & 63;
    int s = (i >> 6) & (S_LEN - 1);
    unsigned v = ((unsigned*)Kb)[i];
    float x0 = bf2f((unsigned short)(v & 0xFFFFu));
    float x1 = bf2f((unsigned short)(v >> 16));
    float c  = fc[((size_t)(sp + s) * 64 + d2) * 2];
    float sn = fc[((size_t)(sp + s) * 64 + d2) * 2 + 1];
    float y0 = x0 * c - x1 * sn;
    float y1 = x0 * sn + x1 * c;
    ((unsigned*)Kb)[i] = (unsigned)f2bf(y0) | ((unsigned)f2bf(y1) << 16);
  }
}

#define BARRIER() __builtin_amdgcn_s_barrier()
#define LGKM0()  do { asm volatile("s_waitcnt lgkmcnt(0)" ::: "memory"); \
                      __builtin_amdgcn_sched_barrier(0); } while (0)
#define VMCNT6() asm volatile("s_waitcnt vmcnt(6)" ::: "memory")
#define VMCNT4() asm volatile("s_waitcnt vmcnt(4)" ::: "memory")
#define VMCNT0() asm volatile("s_waitcnt vmcnt(0)" ::: "memory")

__device__ __forceinline__ bf16x8 ldsrd(const unsigned short* L, int row, int kk, int g) {
  int Xs = (kk * 64 + g * 16) ^ ((row & 7) << 4);
  return *(const bf16x8*)&L[row * 64 + (Xs >> 1)];
}
// wave-cooperative: write 8 rows at rowbase (multiple of 8) of [256][64] tile
__device__ __forceinline__ void stage8(const unsigned short* __restrict__ G, int gbase,
                                       int k0, unsigned short* lds, int rowbase, int lane) {
  int row = rowbase + (lane >> 3);
  int col8 = (lane & 7) ^ ((lane >> 3) & 7);
  async16(G + (size_t)(gbase + row) * 2048 + k0 + col8 * 8, lds + rowbase * 64 + lane * 8);
}

const float SCL2E_H = 0.08838834764831845f * 1.4426950408889634f;  // scale * log2(e)

// ============ Q GEMM: 256x256 4-phase, grid 32x8=256 ============
__global__ __launch_bounds__(512, 2) void k_gemm_q(
    const unsigned short* __restrict__ A, const unsigned short* __restrict__ Bt,
    const float* __restrict__ bq, unsigned short* __restrict__ Qo)
{
  __shared__ __align__(16) unsigned short Abuf[2][256 * 64];
  __shared__ __align__(16) unsigned short Bbuf[2][256 * 64];
  const int NT = 32, NXT = 8;
  const int tid = threadIdx.x, lane = tid & 63, w = tid >> 6;
  const int lr = lane & 15, g = lane >> 4;
  const int wm = w >> 2, wn = w & 3;

  int nwg = NXT * 32;
  int cpx = nwg >> 3;
  int bid = blockIdx.x;
  int swz = (bid & 7) * cpx + (bid >> 3);
  const int by = swz / NXT, bx = swz % NXT;
  const int mbase = by * 256, nbase = bx * 256;

  #define ST_AQ02(tt) if ((tt) < NT) { unsigned short* L = Abuf[(tt) & 1]; int k0 = (tt) * 64; \
    _Pragma("unroll") for (int it = 0; it < 2; ++it) { int sub = it * 8 + w; \
      stage8(A, mbase, k0, L, (sub >> 3) * 128 + (sub & 7) * 8, lane); } }
  #define ST_AQ13(tt) if ((tt) < NT) { unsigned short* L = Abuf[(tt) & 1]; int k0 = (tt) * 64; \
    _Pragma("unroll") for (int it = 0; it < 2; ++it) { int sub = it * 8 + w; \
      stage8(A, mbase, k0, L, 64 + (sub >> 3) * 128 + (sub & 7) * 8, lane); } }
  #define ST_BS0(tt) if ((tt) < NT) { unsigned short* L = Bbuf[(tt) & 1]; int k0 = (tt) * 64; \
    _Pragma("unroll") for (int it = 0; it < 2; ++it) { int sub = it * 8 + w; \
      stage8(Bt, nbase, k0, L, (sub >> 2) * 64 + (sub & 3) * 8, lane); } }
  #define ST_BS1(tt) if ((tt) < NT) { unsigned short* L = Bbuf[(tt) & 1]; int k0 = (tt) * 64; \
    _Pragma("unroll") for (int it = 0; it < 2; ++it) { int sub = it * 8 + w; \
      stage8(Bt, nbase, k0, L, 32 + (sub >> 2) * 64 + (sub & 3) * 8, lane); } }

  f32x4 acc[8][4];
  #pragma unroll
  for (int m = 0; m < 8; ++m)
    #pragma unroll
    for (int n = 0; n < 4; ++n) acc[m][n] = fzero();

  ST_AQ02(0); ST_AQ13(0); ST_BS0(0); ST_BS1(0);
  ST_AQ02(1); ST_BS1(1);
  VMCNT4();
  BARRIER();

  bf16x8 a[2][4], b[2][2];

  for (int t = 0; t < NT; ++t) {
    const unsigned short* Al = Abuf[t & 1];
    const unsigned short* Bl = Bbuf[t & 1];

    #pragma unroll
    for (int kk = 0; kk < 2; ++kk) {
      #pragma unroll
      for (int m = 0; m < 4; ++m) a[kk][m] = ldsrd(Al, wm * 128 + m * 16 + lr, kk, g);
      #pragma unroll
      for (int n = 0; n < 2; ++n) b[kk][n] = ldsrd(Bl, wn * 64 + n * 16 + lr, kk, g);
    }
    ST_AQ13(t + 1);
    BARRIER(); LGKM0();
    __builtin_amdgcn_s_setprio(1);
    #pragma unroll
    for (int kk = 0; kk < 2; ++kk)
      #pragma unroll
      for (int m = 0; m < 4; ++m)
        #pragma unroll
        for (int n = 0; n < 2; ++n)
          acc[m][n] = __builtin_amdgcn_mfma_f32_16x16x32_bf16(a[kk][m], b[kk][n], acc[m][n], 0, 0, 0);
    __builtin_amdgcn_s_setprio(0);
    BARRIER();

    #pragma unroll
    for (int kk = 0; kk < 2; ++kk)
      #pragma unroll
      for (int n = 0; n < 2; ++n) b[kk][n] = ldsrd(Bl, wn * 64 + (2 + n) * 16 + lr, kk, g);
    ST_BS0(t + 1);
    BARRIER(); LGKM0();
    __builtin_amdgcn_s_setprio(1);
    #pragma unroll
    for (int kk = 0; kk < 2; ++kk)
      #pragma unroll
      for (int m = 0; m < 4; ++m)
        #pragma unroll
        for (int n = 0; n < 2; ++n)
          acc[m][2 + n] = __builtin_amdgcn_mfma_f32_16x16x32_bf16(a[kk][m], b[kk][n], acc[m][2 + n], 0, 0, 0);
    __builtin_amdgcn_s_setprio(0);
    BARRIER();

    #pragma unroll
    for (int kk = 0; kk < 2; ++kk)
      #pragma unroll
      for (int m = 0; m < 4; ++m) a[kk][m] = ldsrd(Al, wm * 128 + 64 + m * 16 + lr, kk, g);
    ST_AQ02(t + 2);
    BARRIER(); LGKM0();
    __builtin_amdgcn_s_setprio(1);
    #pragma unroll
    for (int kk = 0; kk < 2; ++kk)
      #pragma unroll
      for (int m = 0; m < 4; ++m)
        #pragma unroll
        for (int n = 0; n < 2; ++n)
          acc[4 + m][2 + n] = __builtin_amdgcn_mfma_f32_16x16x32_bf16(a[kk][m], b[kk][n], acc[4 + m][2 + n], 0, 0, 0);
    __builtin_amdgcn_s_setprio(0);
    BARRIER();

    #pragma unroll
    for (int kk = 0; kk < 2; ++kk)
      #pragma unroll
      for (int n = 0; n < 2; ++n) b[kk][n] = ldsrd(Bl, wn * 64 + n * 16 + lr, kk, g);
    ST_BS1(t + 2);
    VMCNT4();
    BARRIER(); LGKM0();
    __builtin_amdgcn_s_setprio(1);
    #pragma unroll
    for (int kk = 0; kk < 2; ++kk)
      #pragma unroll
      for (int m = 0; m < 4; ++m)
        #pragma unroll
        for (int n = 0; n < 2; ++n)
          acc[4 + m][n] = __builtin_amdgcn_mfma_f32_16x16x32_bf16(a[kk][m], b[kk][n], acc[4 + m][n], 0, 0, 0);
    __builtin_amdgcn_s_setprio(0);
    BARRIER();
  }

  #pragma unroll
  for (int n = 0; n < 4; ++n) {
    const int ng = nbase + wn * 64 + n * 16 + lr;
    const int hh = ng >> 7, dd = ng & 127;
    const float bias = bq[ng];
    #pragma unroll
    for (int m = 0; m < 8; ++m)
      #pragma unroll
      for (int i = 0; i < 4; ++i) {
        int mg = mbase + wm * 128 + m * 16 + g * 4 + i;
        int bb = mg >> 11, s = mg & 2047;
        float val = (acc[m][n][i] + bias) * SCL2E_H;
        Qo[((size_t)(bb * NQH + hh) * S_LEN + s) * HDIM + dd] = f2bf(val);
      }
  }
  #undef ST_AQ02
  #undef ST_AQ13
  #undef ST_BS0
  #undef ST_BS1
}

// ============ KV GEMM: 256x128 2-phase triple-buffered, N=1024, grid 32x8=256 ============
__global__ __launch_bounds__(512, 2) void k_gemm_kv(
    const unsigned short* __restrict__ A, const unsigned short* __restrict__ Bt,
    const float* __restrict__ bk, const float* __restrict__ bv,
    unsigned short* __restrict__ Ko, unsigned short* __restrict__ Vto)
{
  __shared__ __align__(16) unsigned short Ab[3][256 * 64];
  __shared__ __align__(16) unsigned short Bb[3][128 * 64];
  const int NT = 32, NXT = 8;
  const int tid = threadIdx.x, lane = tid & 63, w = tid >> 6;
  const int lr = lane & 15, g = lane >> 4;
  const int wm = w >> 1, wn = w & 1;

  int nwg = NXT * 32;
  int cpx = nwg >> 3;
  int bid = blockIdx.x;
  int swz = (bid & 7) * cpx + (bid >> 3);
  const int by = swz / NXT, bx = swz % NXT;
  const int mbase = by * 256, nbase = bx * 128;

  #define ST_A(tt) { unsigned short* L = Ab[(tt) % 3]; int k0 = (tt) * 64; \
    _Pragma("unroll") for (int it = 0; it < 4; ++it) { int c = tid + it * 512; \
      int row = c >> 3, col8 = (c & 7) ^ (row & 7); \
      async16(A + (size_t)(mbase + row) * 2048 + k0 + col8 * 8, L + c * 8); } }
  #define ST_B(tt) { unsigned short* L = Bb[(tt) % 3]; int k0 = (tt) * 64; \
    _Pragma("unroll") for (int it = 0; it < 2; ++it) { int c = tid + it * 512; \
      int row = c >> 3, col8 = (c & 7) ^ (row & 7); \
      async16(Bt + (size_t)(nbase + row) * 2048 + k0 + col8 * 8, L + c * 8); } }

  f32x4 acc[4][4];
  #pragma unroll
  for (int m = 0; m < 4; ++m)
    #pragma unroll
    for (int n = 0; n < 4; ++n) acc[m][n] = fzero();

  ST_A(0); ST_B(0); ST_A(1); ST_B(1);
  VMCNT6();
  BARRIER();

  for (int t = 0; t < NT; ++t) {
    const unsigned short* Al = Ab[t % 3];
    const unsigned short* Bl = Bb[t % 3];
    bf16x8 a[2][4], b[2][2];

    #pragma unroll
    for (int kk = 0; kk < 2; ++kk) {
      #pragma unroll
      for (int m = 0; m < 4; ++m) a[kk][m] = ldsrd(Al, wm * 64 + m * 16 + lr, kk, g);
      #pragma unroll
      for (int n = 0; n < 2; ++n) b[kk][n] = ldsrd(Bl, wn * 64 + n * 16 + lr, kk, g);
    }
    if (t + 2 < NT) ST_A(t + 2);
    BARRIER(); LGKM0();
    __builtin_amdgcn_s_setprio(1);
    #pragma unroll
    for (int kk = 0; kk < 2; ++kk)
      #pragma unroll
      for (int m = 0; m < 4; ++m)
        #pragma unroll
        for (int n = 0; n < 2; ++n)
          acc[m][n] = __builtin_amdgcn_mfma_f32_16x16x32_bf16(a[kk][m], b[kk][n], acc[m][n], 0, 0, 0);
    __builtin_amdgcn_s_setprio(0);
    BARRIER();

    #pragma unroll
    for (int kk = 0; kk < 2; ++kk)
      #pragma unroll
      for (int n = 0; n < 2; ++n) b[kk][n] = ldsrd(Bl, wn * 64 + (2 + n) * 16 + lr, kk, g);
    if (t + 2 < NT) { ST_B(t + 2); VMCNT6(); } else { VMCNT0(); }
    BARRIER(); LGKM0();
    __builtin_amdgcn_s_setprio(1);
    #pragma unroll
    for (int kk = 0; kk < 2; ++kk)
      #pragma unroll
      for (int m = 0; m < 4; ++m)
        #pragma unroll
        for (int n = 0; n < 2; ++n)
          acc[m][2 + n] = __builtin_amdgcn_mfma_f32_16x16x32_bf16(a[kk][m], b[kk][n], acc[m][2 + n], 0, 0, 0);
    __builtin_amdgcn_s_setprio(0);
    BARRIER();
  }

  #pragma unroll
  for (int n = 0; n < 4; ++n) {
    const int ng = nbase + wn * 64 + n * 16 + lr;        // 0..1023
    const bool isK = (ng < 512);
    const int nn = isK ? ng : ng - 512;
    const int hh = nn >> 7, dd = nn & 127;
    const float bias = isK ? bk[nn] : bv[nn];
    #pragma unroll
    for (int m = 0; m < 4; ++m)
      #pragma unroll
      for (int i = 0; i < 4; ++i) {
        int mg = mbase + wm * 64 + m * 16 + g * 4 + i;
        int bb = mg >> 11, s = mg & 2047;
        float val = acc[m][n][i] + bias;
        if (isK) {
          Ko[((size_t)(bb * NKVH + hh) * S_LEN + s) * HDIM + dd] = f2bf(val);
        } else {
          Vto[((size_t)(bb * NKVH + hh) * HDIM + dd) * S_LEN + s] = f2bf(val);
        }
      }
  }
  #undef ST_A
  #undef ST_B
}

// ============ OUT GEMM: 256x256 4-phase, grid 256 ============
__global__ __launch_bounds__(512, 2) void k_gemm_out256(
    const unsigned short* __restrict__ A, const unsigned short* __restrict__ Bt,
    float* __restrict__ Cf)
{
  __shared__ __align__(16) unsigned short Abuf[2][256 * 64];
  __shared__ __align__(16) unsigned short Bbuf[2][256 * 64];
  const int NT = 32, NXT = 8;
  const int tid = threadIdx.x, lane = tid & 63, w = tid >> 6;
  const int lr = lane & 15, g = lane >> 4;
  const int wm = w >> 2, wn = w & 3;

  int nwg = NXT * 32;
  int cpx = nwg >> 3;
  int bid = blockIdx.x;
  int swz = (bid & 7) * cpx + (bid >> 3);
  const int by = swz / NXT, bx = swz % NXT;
  const int mbase = by * 256, nbase = bx * 256;

  #define ST_AQ02(tt) if ((tt) < NT) { unsigned short* L = Abuf[(tt) & 1]; int k0 = (tt) * 64; \
    _Pragma("unroll") for (int it = 0; it < 2; ++it) { int sub = it * 8 + w; \
      stage8(A, mbase, k0, L, (sub >> 3) * 128 + (sub & 7) * 8, lane); } }
  #define ST_AQ13(tt) if ((tt) < NT) { unsigned short* L = Abuf[(tt) & 1]; int k0 = (tt) * 64; \
    _Pragma("unroll") for (int it = 0; it < 2; ++it) { int sub = it * 8 + w; \
      stage8(A, mbase, k0, L, 64 + (sub >> 3) * 128 + (sub & 7) * 8, lane); } }
  #define ST_BS0(tt) if ((tt) < NT) { unsigned short* L = Bbuf[(tt) & 1]; int k0 = (tt) * 64; \
    _Pragma("unroll") for (int it = 0; it < 2; ++it) { int sub = it * 8 + w; \
      stage8(Bt, nbase, k0, L, (sub >> 2) * 64 + (sub & 3) * 8, lane); } }
  #define ST_BS1(tt) if ((tt) < NT) { unsigned short* L = Bbuf[(tt) & 1]; int k0 = (tt) * 64; \
    _Pragma("unroll") for (int it = 0; it < 2; ++it) { int sub = it * 8 + w; \
      stage8(Bt, nbase, k0, L, 32 + (sub >> 2) * 64 + (sub & 3) * 8, lane); } }

  f32x4 acc[8][4];
  #pragma unroll
  for (int m = 0; m < 8; ++m)
    #pragma unroll
    for (int n = 0; n < 4; ++n) acc[m][n] = fzero();

  ST_AQ02(0); ST_AQ13(0); ST_BS0(0); ST_BS1(0);
  ST_AQ02(1); ST_BS1(1);
  VMCNT4();
  BARRIER();

  bf16x8 a[2][4], b[2][2];

  for (int t = 0; t < NT; ++t) {
    const unsigned short* Al = Abuf[t & 1];
    const unsigned short* Bl = Bbuf[t & 1];

    #pragma unroll
    for (int kk = 0; kk < 2; ++kk) {
      #pragma unroll
      for (int m = 0; m < 4; ++m) a[kk][m] = ldsrd(Al, wm * 128 + m * 16 + lr, kk, g);
      #pragma unroll
      for (int n = 0; n < 2; ++n) b[kk][n] = ldsrd(Bl, wn * 64 + n * 16 + lr, kk, g);
    }
    ST_AQ13(t + 1);
    BARRIER(); LGKM0();
    __builtin_amdgcn_s_setprio(1);
    #pragma unroll
    for (int kk = 0; kk < 2; ++kk)
      #pragma unroll
      for (int m = 0; m < 4; ++m)
        #pragma unroll
        for (int n = 0; n < 2; ++n)
          acc[m][n] = __builtin_amdgcn_mfma_f32_16x16x32_bf16(a[kk][m], b[kk][n], acc[m][n], 0, 0, 0);
    __builtin_amdgcn_s_setprio(0);
    BARRIER();

    #pragma unroll
    for (int kk = 0; kk < 2; ++kk)
      #pragma unroll
      for (int n = 0; n < 2; ++n) b[kk][n] = ldsrd(Bl, wn * 64 + (2 + n) * 16 + lr, kk, g);
    ST_BS0(t + 1);
    BARRIER(); LGKM0();
    __builtin_amdgcn_s_setprio(1);
    #pragma unroll
    for (int kk = 0; kk < 2; ++kk)
      #pragma unroll
      for (int m = 0; m < 4; ++m)
        #pragma unroll
        for (int n = 0; n < 2; ++n)
          acc[m][2 + n] = __builtin_amdgcn_mfma_f32_16x16x32_bf16(a[kk][m], b[kk][n], acc[m][2 + n], 0, 0, 0);
    __builtin_amdgcn_s_setprio(0);
    BARRIER();

    #pragma unroll
    for (int kk = 0; kk < 2; ++kk)
      #pragma unroll
      for (int m = 0; m < 4; ++m) a[kk][m] = ldsrd(Al, wm * 128 + 64 + m * 16 + lr, kk, g);
    ST_AQ02(t + 2);
    BARRIER(); LGKM0();
    __builtin_amdgcn_s_setprio(1);
    #pragma unroll
    for (int kk = 0; kk < 2; ++kk)
      #pragma unroll
      for (int m = 0; m < 4; ++m)
        #pragma unroll
        for (int n = 0; n < 2; ++n)
          acc[4 + m][2 + n] = __builtin_amdgcn_mfma_f32_16x16x32_bf16(a[kk][m], b[kk][n], acc[4 + m][2 + n], 0, 0, 0);
    __builtin_amdgcn_s_setprio(0);
    BARRIER();

    #pragma unroll
    for (int kk = 0; kk < 2; ++kk)
      #pragma unroll
      for (int n = 0; n < 2; ++n) b[kk][n] = ldsrd(Bl, wn * 64 + n * 16 + lr, kk, g);
    ST_BS1(t + 2);
    VMCNT4();
    BARRIER(); LGKM0();
    __builtin_amdgcn_s_setprio(1);
    #pragma unroll
    for (int kk = 0; kk < 2; ++kk)
      #pragma unroll
      for (int m = 0; m < 4; ++m)
        #pragma unroll
        for (int n = 0; n < 2; ++n)
          acc[4 + m][n] = __builtin_amdgcn_mfma_f32_16x16x32_bf16(a[kk][m], b[kk][n], acc[4 + m][n], 0, 0, 0);
    __builtin_amdgcn_s_setprio(0);
    BARRIER();
  }

  #pragma unroll
  for (int m = 0; m < 8; ++m)
    #pragma unroll
    for (int n = 0; n < 4; ++n)
      #pragma unroll
      for (int i = 0; i < 4; ++i) {
        int mg = mbase + wm * 128 + m * 16 + g * 4 + i;
        int ng = nbase + wn * 64 + n * 16 + lr;
        Cf[(size_t)mg * 2048 + ng] = acc[m][n][i];
      }
  #undef ST_AQ02
  #undef ST_AQ13
  #undef ST_BS0
  #undef ST_BS1
}

// ---------- flash v9b: 8 waves x 32 q-rows (QBLK=256), 64KB LDS, launch_bounds(512,2),
// fused Q-rope, exp2 domain, defer-max, diag-only mask ----------
// grid 256 = 64 bh x 4 tile-pairs {tp, 7-tp}; 36 KV-iters per block.
__global__ __launch_bounds__(512, 2) void k_flash2(
    const unsigned short* __restrict__ Q, const unsigned short* __restrict__ K,
    const unsigned short* __restrict__ Vt, unsigned short* __restrict__ O,
    const float* __restrict__ fc, const int* __restrict__ start_pos)
{
  __shared__ __align__(16) unsigned short SH[32768];  // 64KB: 2 x (K 16KB + V 16KB); epilogue reuses

  const int tid = threadIdx.x;
  const int lane = tid & 63;
  const int w = tid >> 6;        // 0..7
  const int ql = lane & 31;
  const int hi = lane >> 5;

  const int bh = blockIdx.x >> 2;
  const int tp = blockIdx.x & 3;
  const int b = bh >> 4, h = bh & 15;
  const int kh = h >> 2;
  const int sp = start_pos[0];

  const unsigned short* Qbase = Q + (size_t)(b * NQH + h) * S_LEN * HDIM;
  const unsigned short* Kbase = K + (size_t)(b * NKVH + kh) * S_LEN * HDIM;
  const unsigned short* Vtb   = Vt + (size_t)(b * NKVH + kh) * HDIM * S_LEN;

  // stage KV tile jj into buffer jj&1 (4 loads/thread: 2 K + 2 V)
  #define STAGEKV(jj) { unsigned short* Kd = SH + ((jj) & 1) * 16384; \
    unsigned short* Vd = Kd + 8192; \
    _Pragma("unroll") for (int it = 0; it < 2; ++it) { \
      int c = tid + it * 512; int row = c >> 4, col = c & 15; \
      int lcol = (col & 8) | ((col ^ (row & 7)) & 7); \
      async16(Kbase + (size_t)((jj) * 64 + row) * HDIM + lcol * 8, Kd + c * 8); } \
    _Pragma("unroll") for (int it = 0; it < 2; ++it) { \
      int c = tid + it * 512; int row = c >> 3, col = c & 7; \
      int lcol = col ^ (row & 7); \
      async16(Vtb + (size_t)row * S_LEN + (jj) * 64 + lcol * 8, Vd + c * 8); } }

  #pragma unroll 1
  for (int half = 0; half < 2; ++half) {
    const int t = half ? (7 - tp) : tp;
    const int nkv = 4 * t + 4;
    const int qg = t * 256 + w * 32 + ql;
    const int jd = 4 * t + (w >> 1);   // wave's diagonal iteration
    const int ql2 = (w & 1) * 32 + ql; // q row within the diagonal 64-block

    __syncthreads();  // protect LDS reuse across halves

    // Q load + in-register RoPE (pairs (2u,2u+1) are lane-local in the fragment)
    bf16x8 qf[8];
    {
      const unsigned short* qp = Qbase + (size_t)qg * HDIM;
      const float* fcrow = fc + (size_t)(sp + qg) * 128;
      #pragma unroll
      for (int dd = 0; dd < 8; ++dd) {
        bf16x8 raw = *(const bf16x8*)(qp + dd * 16 + hi * 8);
        int d2b = (dd * 16 + hi * 8) >> 1;
        union { unsigned u[4]; bf16x8 v; } out;
        #pragma unroll
        for (int u2 = 0; u2 < 4; ++u2) {
          float x0 = bf2f((unsigned short)raw[2 * u2]);
          float x1 = bf2f((unsigned short)raw[2 * u2 + 1]);
          float2 cs = *(const float2*)&fcrow[(d2b + u2) * 2];
          out.u[u2] = cvtpk(x0 * cs.x - x1 * cs.y, x0 * cs.y + x1 * cs.x);
        }
        qf[dd] = out.v;
      }
    }

    float m_r = -1e30f, l_r = 0.f;
    f32x16 oA[4];
    #pragma unroll
    for (int db = 0; db < 4; ++db)
      #pragma unroll
      for (int r = 0; r < 16; ++r) oA[db][r] = 0.f;

    STAGEKV(0);
    __syncthreads();

    for (int j = 0; j < nkv; ++j) {
      const unsigned short* Kl = SH + (j & 1) * 16384;
      const unsigned short* Vl = Kl + 8192;

      if (j + 1 < nkv) STAGEKV(j + 1);

      if (j <= jd) {
        f32x16 p0, p1;
        #pragma unroll
        for (int r = 0; r < 16; ++r) { p0[r] = 0.f; p1[r] = 0.f; }
        __builtin_amdgcn_s_setprio(1);
        #pragma unroll
        for (int dd = 0; dd < 8; ++dd) {
          const int off = (((dd * 32 + hi * 16) ^ ((ql & 7) << 4)) >> 1);
          bf16x8 a0 = *(const bf16x8*)&Kl[ql * 128 + off];
          bf16x8 a1 = *(const bf16x8*)&Kl[(32 + ql) * 128 + off];
          p0 = __builtin_amdgcn_mfma_f32_32x32x16_bf16(a0, qf[dd], p0, 0, 0, 0);
          p1 = __builtin_amdgcn_mfma_f32_32x32x16_bf16(a1, qf[dd], p1, 0, 0, 0);
        }
        __builtin_amdgcn_s_setprio(0);

        // causal mask: diagonal iteration only (j<jd needs none; j>jd skipped)
        if (j == jd) {
          #pragma unroll
          for (int r = 0; r < 16; ++r) {
            const int klh = (r & 3) + 8 * (r >> 2) + 4 * hi;
            if (klh > ql2) p0[r] = -1e30f;
            if (klh + 32 > ql2) p1[r] = -1e30f;
          }
        }

        // online softmax with defer-max (THR=8 in log2 domain)
        float pm = -1e30f;
        #pragma unroll
        for (int r = 0; r < 16; ++r) pm = fmaxf(pm, fmaxf(p0[r], p1[r]));
        pm = fmaxf(pm, __shfl_xor(pm, 32));
        if (!__all(pm - m_r <= 8.0f)) {
          const float mn = fmaxf(m_r, pm);
          const float corr = exp2f(m_r - mn);
          m_r = mn;
          l_r *= corr;
          #pragma unroll
          for (int db = 0; db < 4; ++db)
            #pragma unroll
            for (int r = 0; r < 16; ++r) oA[db][r] *= corr;
        }
        float rs = 0.f;
        #pragma unroll
        for (int r = 0; r < 16; ++r) {
          p0[r] = exp2f(p0[r] - m_r);
          p1[r] = exp2f(p1[r] - m_r);
          rs += p0[r] + p1[r];
        }
        rs += __shfl_xor(rs, 32);
        l_r += rs;

        bf16x8 pb[4];
        {
          unsigned Wv[8], W2v[8];
          #pragma unroll
          for (int d = 0; d < 4; ++d) {
            Wv[d]      = cvtpk(p0[4*d],     p0[4*d + 1]);
            W2v[d]     = cvtpk(p0[4*d + 2], p0[4*d + 3]);
            Wv[4 + d]  = cvtpk(p1[4*d],     p1[4*d + 1]);
            W2v[4 + d] = cvtpk(p1[4*d + 2], p1[4*d + 3]);
          }
          #pragma unroll
          for (int kt = 0; kt < 2; ++kt) {
            #pragma unroll
            for (int s = 0; s < 2; ++s) {
              unsigned ownW   = hi ? Wv[kt*4 + 2*s + 1]  : Wv[kt*4 + 2*s];
              unsigned sendW  = hi ? Wv[kt*4 + 2*s]      : Wv[kt*4 + 2*s + 1];
              unsigned recvW  = (unsigned)__shfl_xor((int)sendW, 32);
              unsigned ownW2  = hi ? W2v[kt*4 + 2*s + 1] : W2v[kt*4 + 2*s];
              unsigned sendW2 = hi ? W2v[kt*4 + 2*s]     : W2v[kt*4 + 2*s + 1];
              unsigned recvW2 = (unsigned)__shfl_xor((int)sendW2, 32);
              union { unsigned u[4]; bf16x8 v; } pk;
              pk.u[0] = hi ? recvW  : ownW;
              pk.u[1] = hi ? recvW2 : ownW2;
              pk.u[2] = hi ? ownW   : recvW;
              pk.u[3] = hi ? ownW2  : recvW2;
              pb[kt*2 + s] = pk.v;
            }
          }
        }

        __builtin_amdgcn_s_setprio(1);
        #pragma unroll
        for (int ks = 0; ks < 4; ++ks) {
          #pragma unroll
          for (int db = 0; db < 4; ++db) {
            const int off = (((ks * 32 + hi * 16) ^ ((ql & 7) << 4)) >> 1);
            bf16x8 av = *(const bf16x8*)&Vl[(db * 32 + ql) * 64 + off];
            oA[db] = __builtin_amdgcn_mfma_f32_32x32x16_bf16(av, pb[ks], oA[db], 0, 0, 0);
          }
        }
        __builtin_amdgcn_s_setprio(0);
      }
      __syncthreads();
    }

    // epilogue: O^T -> LDS (transpose, swizzled) -> coalesced global (256 rows x 256B = 64KB)
    {
      const float invl = 1.f / l_r;
      const int qloc = w * 32 + ql;
      #pragma unroll
      for (int db = 0; db < 4; ++db)
        #pragma unroll
        for (int g4 = 0; g4 < 4; ++g4) {
          unsigned lo  = cvtpk(oA[db][g4*4 + 0] * invl, oA[db][g4*4 + 1] * invl);
          unsigned hi2 = cvtpk(oA[db][g4*4 + 2] * invl, oA[db][g4*4 + 3] * invl);
          int byteoff = qloc * 256 + ((db * 64 + g4 * 16 + hi * 8) ^ ((qloc & 7) << 4));
          *(uint2*)((char*)SH + byteoff) = make_uint2(lo, hi2);
        }
    }
    __syncthreads();
    {
      const int q2 = tid >> 1, hf = tid & 1;
      unsigned short* orow = O + ((size_t)(b * S_LEN + t * 256 + q2)) * D_MODEL + h * HDIM + hf * 64;
      #pragma unroll
      for (int u = 0; u < 8; ++u) {
        int byteoff = q2 * 256 + ((hf * 128 + u * 16) ^ ((q2 & 7) << 4));
        bf16x8 v = *(const bf16x8*)((const char*)SH + byteoff);
        *(bf16x8*)(orow + u * 8) = v;
      }
    }
  }
  #undef STAGEKV
}

// ---------- launch ----------
extern "C" void kernel_launch(void* const* d_in, const int* in_sizes, int n_in,
                              void* d_out, int out_size, void* d_ws, size_t ws_size,
                              hipStream_t stream) {
  (void)in_sizes; (void)n_in; (void)out_size; (void)ws_size;
  const float* x  = (const float*)d_in[0];
  const float* fc = (const float*)d_in[1];
  const float* Wq = (const float*)d_in[2];
  const float* bq = (const float*)d_in[3];
  const float* Wk = (const float*)d_in[4];
  const float* bk = (const float*)d_in[5];
  const float* Wv = (const float*)d_in[6];
  const float* bv = (const float*)d_in[7];
  const float* Wo = (const float*)d_in[8];
  const int* start_pos = (const int*)d_in[9];
  float* out = (float*)d_out;

  unsigned short* ws = (unsigned short*)d_ws;
  size_t off = 0;
  unsigned short* xb  = ws + off; off += (size_t)8192 * 2048;
  unsigned short* Wt  = ws + off; off += (size_t)3072 * 2048;
  unsigned short* Wot = ws + off; off += (size_t)2048 * 2048;
  unsigned short* Qb  = ws + off; off += (size_t)BATCH * NQH  * S_LEN * HDIM;
  unsigned short* Kb  = ws + off; off += (size_t)BATCH * NKVH * S_LEN * HDIM;
  unsigned short* Vtb = ws + off; off += (size_t)BATCH * NKVH * S_LEN * HDIM;
  unsigned short* Ob  = ws + off; off += (size_t)8192 * 2048;

  k_convert_x<<<2048, 256, 0, stream>>>(x, xb, 8192 * 2048 / 4);
  k_transpose_all<<<10240, 256, 0, stream>>>(Wq, Wk, Wv, Wo, Wt, Wot);

  k_gemm_q<<<dim3(256), 512, 0, stream>>>(xb, Wt, bq, Qb);
  k_gemm_kv<<<dim3(256), 512, 0, stream>>>(xb, Wt + (size_t)2048 * 2048, bk, bv, Kb, Vtb);

  k_ropeK<<<512, 256, 0, stream>>>(Kb, fc, start_pos, BATCH * NKVH * S_LEN * 64);

  k_flash2<<<dim3(256), 512, 0, stream>>>(Qb, Kb, Vtb, Ob, fc, start_pos);

  k_gemm_out256<<<dim3(256), 512, 0, stream>>>(Ob, Wot, out);
}